// Round 9
// baseline (943.604 us; speedup 1.0000x reference)
//
#include <hip/hip_runtime.h>
#include <math.h>

#define S_LEN 512
#define B_SZ  256

typedef _Float16 f16x8 __attribute__((ext_vector_type(8)));
typedef _Float16 h2    __attribute__((ext_vector_type(2)));
typedef float    f32x4 __attribute__((ext_vector_type(4)));

__device__ __forceinline__ float sigm(float x) { return 1.0f / (1.0f + __expf(-x)); }

__device__ __forceinline__ float fdot2(h2 a, h2 b, float c) {
#if __has_builtin(__builtin_amdgcn_fdot2)
    return __builtin_amdgcn_fdot2(a, b, c, false);
#else
    return c + (float)a.x * (float)b.x + (float)a.y * (float)b.y;
#endif
}

// bit-reinterpret one float lane as a packed h2
#define H2C(f) __builtin_bit_cast(h2, f)
// 4 fdot2 along one float4(=4 h2) weight/act pair
#define DOT4(acc, W, H) do { \
    acc = fdot2(H2C((H).x), H2C((W).x), acc); \
    acc = fdot2(H2C((H).y), H2C((W).y), acc); \
    acc = fdot2(H2C((H).z), H2C((W).z), acc); \
    acc = fdot2(H2C((H).w), H2C((W).w), acc); } while (0)

// quad_perm butterfly add: after both, all 4 lanes of the quad hold the quad sum.
__device__ __forceinline__ float qsum1(float x) {
    int yi = __builtin_amdgcn_update_dpp(0, __builtin_bit_cast(int, x), 0xB1, 0xF, 0xF, true);
    return x + __builtin_bit_cast(float, yi);
}
__device__ __forceinline__ float qsum2(float x) {
    int yi = __builtin_amdgcn_update_dpp(0, __builtin_bit_cast(int, x), 0x4E, 0xF, 0xF, true);
    return x + __builtin_bit_cast(float, yi);
}
__device__ __forceinline__ float qsum(float x) { return qsum2(qsum1(x)); }

// raw barrier: drain LDS only; global loads/stores stay in flight
#define LBAR() do { \
    asm volatile("s_waitcnt lgkmcnt(0)" ::: "memory"); \
    __builtin_amdgcn_s_barrier(); \
    asm volatile("" ::: "memory"); \
} while (0)

// LDS tile byte offset with G4 XOR swizzle: row-major [128 rows][128 B]
__device__ __forceinline__ int swz(int row, int byte_in_row) {
    return row * 128 + (byte_in_row ^ ((row & 7) << 4));
}

// ---------------- pack: fp16 tables + packed weights (per-thread scan pack) -------
__global__ void k_pack16(const float* __restrict__ W1, const float* __restrict__ Wd,
                         const float* __restrict__ W2, const float* __restrict__ W3,
                         const float* __restrict__ W4, const float* __restrict__ b2,
                         const float* __restrict__ b3, const float* __restrict__ b4,
                         const float* __restrict__ h0, const float* __restrict__ Wa,
                         const float* __restrict__ Eq, const float* __restrict__ Eut,
                         const float* __restrict__ Eit,
                         _Float16* __restrict__ Eq16, _Float16* __restrict__ Eut16,
                         _Float16* __restrict__ Eit16,
                         _Float16* __restrict__ Wld16, _Float16* __restrict__ Wz16,
                         h2* __restrict__ Wa16p, h2* __restrict__ Wsc,
                         float* __restrict__ bz, float* __restrict__ w1csum,
                         float* __restrict__ hcarry, float* __restrict__ pred)
{
    int idx0 = blockIdx.x * blockDim.x + threadIdx.x;
    int stride = gridDim.x * blockDim.x;
    for (int i = idx0; i < 10001 * 128; i += stride) Eq16[i] = (_Float16)Eq[i];
    for (int i = idx0; i < 1025 * 128; i += stride) Eut16[i] = (_Float16)Eut[i];
    for (int i = idx0; i < 1025 * 128; i += stride) Eit16[i] = (_Float16)Eit[i];
    for (int idx = idx0; idx < 256 * 256; idx += stride) {
        int c = idx >> 8, j = idx & 255;
        float v;
        if (c < 128) v = W1[c * 306 + j];
        else         v = (j < 128) ? Wd[(c - 128) * 128 + j] : 0.f;
        Wld16[idx] = (_Float16)v;
    }
    for (int idx = idx0; idx < 384 * 384; idx += stride) {
        int c = idx / 384, j = idx - c * 384;
        float v;
        if (c < 128)      v = W2[c * 512 + j];
        else if (c < 256) v = W3[(c - 128) * 512 + j];
        else              v = (j >= 128 && j < 256) ? W4[(c - 256) * 384 + 128 + j] : 0.f;
        Wz16[idx] = (_Float16)v;
    }
    for (int idx = idx0; idx < 128 * 64; idx += stride) {
        int c = idx >> 6, j = idx & 63;
        h2 v; v.x = (_Float16)Wa[c * 128 + 2 * j]; v.y = (_Float16)Wa[c * 128 + 2 * j + 1];
        Wa16p[idx] = v;
    }
    // per-thread scan weights for k_scan v8: slot = tid (1024 slots), 32 h2 each.
    // r = slot>>9, k = (slot>>2)&127, q = slot&3.
    // r0: e[0,16)=W2h[k][q], e[16,32)=W3h[k][q]; r1: e[0,16)=W4h, e[16,32)=W4l.
    for (int idx = idx0; idx < 1024 * 32; idx += stride) {
        int slot = idx >> 5, e = idx & 31;
        int q = slot & 3, kk = (slot >> 2) & 127, r = slot >> 9;
        int grp = e >> 4;
        int j = q * 32 + (e & 15) * 2;
        const float* src;
        if (r == 0) src = (grp == 0) ? (W2 + kk * 512 + 384 + j) : (W3 + kk * 512 + 384 + j);
        else        src = (grp == 0) ? (W4 + kk * 384 + j)       : (W4 + kk * 384 + 128 + j);
        h2 v; v.x = (_Float16)src[0]; v.y = (_Float16)src[1];
        Wsc[idx] = v;
    }
    for (int idx = idx0; idx < 384; idx += stride)
        bz[idx] = (idx < 128) ? b2[idx] : (idx < 256 ? b3[idx - 128] : b4[idx - 256]);
    for (int idx = idx0; idx < 128; idx += stride) {
        float s = 0.f;
        for (int j = 0; j < 50; ++j) s += W1[idx * 306 + 256 + j];
        w1csum[idx] = s;
    }
    for (int idx = idx0; idx < 256 * 128; idx += stride) hcarry[idx] = h0[idx];
    for (int idx = idx0; idx < 256; idx += stride) pred[(size_t)idx * S_LEN] = 0.f;
}

// ---------------- disc: sigmoid(q . Wdisc + bdisc) * 10 (f32, full sequence) ------
__global__ __launch_bounds__(256) void k_disc(const int* __restrict__ qseq,
                                              const float* __restrict__ Eq,
                                              const float* __restrict__ Wdisc,
                                              const float* __restrict__ bdisc,
                                              float* __restrict__ disc)
{
    __shared__ float wd[128];
    __shared__ float bds;
    if (threadIdx.x < 128) wd[threadIdx.x] = Wdisc[threadIdx.x];
    if (threadIdx.x == 0) bds = bdisc[0];
    __syncthreads();
    int r = blockIdx.x * 64 + (threadIdx.x >> 2);
    int q4 = threadIdx.x & 3;
    const float* qe = Eq + (size_t)qseq[r] * 128 + q4 * 32;
    float s = 0.f;
#pragma unroll
    for (int j = 0; j < 32; ++j) s = fmaf(qe[j], wd[q4 * 32 + j], s);
    s += __shfl_xor(s, 1, 64);
    s += __shfl_xor(s, 2, 64);
    if (q4 == 0) disc[r] = sigm(s + bds) * 10.0f;
}

// ---------------- MFMA GEMM 1: learn (cb=0) / diff (cb=1); K=256 ------------------
__global__ __launch_bounds__(256) void k_mm_ld(
    const int* __restrict__ qseq, const int* __restrict__ utseq, const int* __restrict__ cseq,
    const _Float16* __restrict__ Eq16, const _Float16* __restrict__ Eut16,
    const _Float16* __restrict__ Wld16, const float* __restrict__ b1,
    const float* __restrict__ bd, const float* __restrict__ w1csum,
    _Float16* __restrict__ learn16, _Float16* __restrict__ diff16,
    int s_lo, int out_row0)
{
    __shared__ _Float16 As[128 * 64];
    __shared__ _Float16 Bs[128 * 64];
    __shared__ int   ridxq[128];
    __shared__ int   ridxut[128];
    __shared__ float rcorr[128];
    __shared__ float cS[128];
    __shared__ float c2S[128];

    const int tid = threadIdx.x;
    const int vr0 = blockIdx.x * 128;
    const int cb = blockIdx.y;

    if (tid < 128) {
        int vr = vr0 + tid;
        int b = vr & 255, s = s_lo + (vr >> 8);
        int rin = b * S_LEN + s;
        ridxq[tid] = qseq[rin];
        ridxut[tid] = utseq[rin];
        rcorr[tid] = (float)cseq[rin];
        cS[tid] = (cb == 0) ? w1csum[tid] : 0.f;
        c2S[tid] = (cb == 0) ? b1[tid] : bd[tid];
    }
    __syncthreads();

    const int wid = tid >> 6, lane = tid & 63;
    const int wr = wid >> 1, wc = wid & 1;
    const int lrow = lane & 15, lkg = lane >> 4;
    const int arow = tid >> 1, apart = tid & 1;

    f32x4 acc[4][4];
#pragma unroll
    for (int i = 0; i < 4; ++i)
#pragma unroll
        for (int j = 0; j < 4; ++j) acc[i][j] = (f32x4){0.f, 0.f, 0.f, 0.f};

    for (int kb = 0; kb < 4; ++kb) {
        int k0 = kb * 64;
        const _Float16* srcA = (k0 < 128)
            ? (Eq16 + (size_t)ridxq[arow] * 128 + k0 + apart * 32)
            : (Eut16 + (size_t)ridxut[arow] * 128 + (k0 - 128) + apart * 32);
        const _Float16* srcB = Wld16 + (size_t)(cb * 128 + arow) * 256 + k0 + apart * 32;
#pragma unroll
        for (int j = 0; j < 4; ++j) {
            float4 va = *(const float4*)(srcA + j * 8);
            float4 vb = *(const float4*)(srcB + j * 8);
            int boff = apart * 64 + j * 16;
            *(float4*)((char*)As + swz(arow, boff)) = va;
            *(float4*)((char*)Bs + swz(arow, boff)) = vb;
        }
        __syncthreads();
#pragma unroll
        for (int ks = 0; ks < 2; ++ks) {
            f16x8 af[4], bf[4];
#pragma unroll
            for (int f = 0; f < 4; ++f) {
                int ar = wr * 64 + f * 16 + lrow;
                af[f] = *(const f16x8*)((const char*)As + swz(ar, ks * 64 + lkg * 16));
                int br = wc * 64 + f * 16 + lrow;
                bf[f] = *(const f16x8*)((const char*)Bs + swz(br, ks * 64 + lkg * 16));
            }
#pragma unroll
            for (int fi = 0; fi < 4; ++fi)
#pragma unroll
                for (int fj = 0; fj < 4; ++fj)
                    acc[fi][fj] = __builtin_amdgcn_mfma_f32_16x16x32_f16(
                        af[fi], bf[fj], acc[fi][fj], 0, 0, 0);
        }
        __syncthreads();
    }

    if (cb == 0) {
#pragma unroll
        for (int fi = 0; fi < 4; ++fi) {
#pragma unroll
            for (int r = 0; r < 4; ++r) {
                int lr_ = wr * 64 + fi * 16 + (lane >> 4) * 4 + r;
                int grow = vr0 + out_row0 + lr_;
                float corr = rcorr[lr_];
#pragma unroll
                for (int fj = 0; fj < 4; ++fj) {
                    int col = wc * 64 + fj * 16 + (lane & 15);
                    float v = acc[fi][fj][r] + corr * cS[col] + c2S[col];
                    learn16[(size_t)grow * 128 + col] = (_Float16)v;
                }
            }
        }
    } else {
#pragma unroll
        for (int fi = 0; fi < 4; ++fi) {
#pragma unroll
            for (int r = 0; r < 4; ++r) {
                int lr_ = wr * 64 + fi * 16 + (lane >> 4) * 4 + r;
                int grow = vr0 + out_row0 + lr_;
#pragma unroll
                for (int fj = 0; fj < 4; ++fj) {
                    int col = wc * 64 + fj * 16 + (lane & 15);
                    float v = sigm(acc[fi][fj][r] + c2S[col]);
                    diff16[(size_t)grow * 128 + col] = (_Float16)v;
                }
            }
        }
    }
}

// ---------------- MFMA GEMM 2: U16[ur, cb*128..] , K=384 --------------------------
__global__ __launch_bounds__(256) void k_mm_u(
    const int* __restrict__ itseq, const _Float16* __restrict__ Eit16,
    const _Float16* __restrict__ learn16, const _Float16* __restrict__ Wz16,
    const float* __restrict__ bz, _Float16* __restrict__ U16, int t0)
{
    __shared__ _Float16 As[128 * 64];
    __shared__ _Float16 Bs[128 * 64];
    __shared__ int   itidx[128];
    __shared__ float bzS[128];

    const int tid = threadIdx.x;
    const int ur0 = blockIdx.x * 128;
    const int cb = blockIdx.y;
    const int t = t0 + (ur0 >> 8);
    const bool tzero = (t == 0);

    if (tid < 128) {
        int b = (ur0 + tid) & 255;
        itidx[tid] = itseq[b * S_LEN + t];
        bzS[tid] = bz[cb * 128 + tid];
    }
    __syncthreads();

    const int wid = tid >> 6, lane = tid & 63;
    const int wr = wid >> 1, wc = wid & 1;
    const int lrow = lane & 15, lkg = lane >> 4;
    const int arow = tid >> 1, apart = tid & 1;

    f32x4 acc[4][4];
#pragma unroll
    for (int i = 0; i < 4; ++i)
#pragma unroll
        for (int j = 0; j < 4; ++j) acc[i][j] = (f32x4){0.f, 0.f, 0.f, 0.f};

    for (int kb = 0; kb < 6; ++kb) {
        int k0 = kb * 64;
        int sec = k0 >> 7;
        int off = (k0 & 127) + apart * 32;
        const _Float16* srcA;
        if (sec == 0)      srcA = tzero ? nullptr : (learn16 + (size_t)(ur0 + arow) * 128 + off);
        else if (sec == 1) srcA = Eit16 + (size_t)itidx[arow] * 128 + off;
        else               srcA = learn16 + (size_t)(ur0 + arow + 256) * 128 + off;
        const _Float16* srcB = Wz16 + (size_t)(cb * 128 + arow) * 384 + k0 + apart * 32;
#pragma unroll
        for (int j = 0; j < 4; ++j) {
            float4 va;
            if (srcA) va = *(const float4*)(srcA + j * 8);
            else { va.x = va.y = va.z = va.w = 0.f; }
            float4 vb = *(const float4*)(srcB + j * 8);
            int boff = apart * 64 + j * 16;
            *(float4*)((char*)As + swz(arow, boff)) = va;
            *(float4*)((char*)Bs + swz(arow, boff)) = vb;
        }
        __syncthreads();
#pragma unroll
        for (int ks = 0; ks < 2; ++ks) {
            f16x8 af[4], bf[4];
#pragma unroll
            for (int f = 0; f < 4; ++f) {
                int ar = wr * 64 + f * 16 + lrow;
                af[f] = *(const f16x8*)((const char*)As + swz(ar, ks * 64 + lkg * 16));
                int br = wc * 64 + f * 16 + lrow;
                bf[f] = *(const f16x8*)((const char*)Bs + swz(br, ks * 64 + lkg * 16));
            }
#pragma unroll
            for (int fi = 0; fi < 4; ++fi)
#pragma unroll
                for (int fj = 0; fj < 4; ++fj)
                    acc[fi][fj] = __builtin_amdgcn_mfma_f32_16x16x32_f16(
                        af[fi], bf[fj], acc[fi][fj], 0, 0, 0);
        }
        __syncthreads();
    }

#pragma unroll
    for (int fi = 0; fi < 4; ++fi) {
#pragma unroll
        for (int r = 0; r < 4; ++r) {
            int lr_ = wr * 64 + fi * 16 + (lane >> 4) * 4 + r;
            int grow = ur0 + lr_;
#pragma unroll
            for (int fj = 0; fj < 4; ++fj) {
                int col = wc * 64 + fj * 16 + (lane & 15);
                float v = acc[fi][fj][r] + bzS[col];
                U16[(size_t)grow * 384 + cb * 128 + col] = (_Float16)v;
            }
        }
    }
}

// ---------------- scan v8: 1024 thr, wave-level role split (r0:{W2,W3}, r1:{W4}) --
__global__ __launch_bounds__(1024) __attribute__((amdgpu_waves_per_eu(4, 4)))
void k_scan(_Float16* __restrict__ U16, float* __restrict__ hcarry,
            const h2* __restrict__ Wsc, int T_len)
{
    const int b = blockIdx.x;
    const int tid = threadIdx.x;
    const int k = (tid >> 2) & 127;  // output channel
    const int q = tid & 3;           // j-quarter (32 elems = 16 h2)
    const int r = tid >> 9;          // wave role: 0 -> {W2h,W3h}, 1 -> {W4h,W4l}

    // 32 h2 of weights in 8 NAMED float4 locals
    const float4* wsrc = (const float4*)(Wsc + (size_t)tid * 32);
    float4 wA0 = wsrc[0], wA1 = wsrc[1], wA2 = wsrc[2], wA3 = wsrc[3];  // r0:W2h r1:W4h
    float4 wB0 = wsrc[4], wB1 = wsrc[5], wB2 = wsrc[6], wB3 = wsrc[7];  // r0:W3h r1:W4l

    __shared__ float4 hpv[16];   // 128 halfs of h (fp16 packed)
    __shared__ float4 lgv[16];   // 128 halfs of LG (fp16 packed, for dots)
    __shared__ float  lgs[128];  // f32 LG scalars (precision of the h-recurrence)

    float h_k = hcarry[b * 128 + k];   // carried f32 state (used by r1)
    if (tid < 64) {
        h2 v;
        v.x = (_Float16)hcarry[b * 128 + 2 * tid];
        v.y = (_Float16)hcarry[b * 128 + 2 * tid + 1];
        ((h2*)hpv)[tid] = v;
    }
    __syncthreads();

    _Float16* Ub = U16 + (size_t)b * 384;
    // role-specific u prefetch: r0 needs u2,u3 ; r1 needs u4
    float uAc = 0.f, uBc = 0.f;
    if (r == 0) { uAc = (float)Ub[k]; uBc = (float)Ub[128 + k]; }
    else        { uAc = (float)Ub[256 + k]; }

    for (int lt = 0; lt < T_len; ++lt) {
        float uAn = 0.f, uBn = 0.f;
        if (lt + 1 < T_len) {
            const _Float16* Un = Ub + (size_t)(lt + 1) * (B_SZ * 384);
            if (r == 0) { uAn = (float)Un[k]; uBn = (float)Un[128 + k]; }
            else        { uAn = (float)Un[256 + k]; }
        }

        // ---- phase 1: dots over h quarter
        float4 hq0 = hpv[q * 4 + 0], hq1 = hpv[q * 4 + 1],
               hq2 = hpv[q * 4 + 2], hq3 = hpv[q * 4 + 3];
        float sa = 0.f, sb = 0.f, sc = 0.f, sd = 0.f;
        DOT4(sa, wA0, hq0); DOT4(sb, wA1, hq1); DOT4(sa, wA2, hq2); DOT4(sb, wA3, hq3);
        if (r == 0) {
            DOT4(sc, wB0, hq0); DOT4(sd, wB1, hq1); DOT4(sc, wB2, hq2); DOT4(sd, wB3, hq3);
        }
        float sA = qsum(sa + sb);   // r0: s2 ; r1: s4
        if (r == 0) {
            float sB = qsum(sc + sd);   // s3
            float LG_k = sigm(sB + uBc) * sigm(2.f * (sA + uAc));
            if (q == 0) {
                ((_Float16*)lgv)[k] = (_Float16)LG_k;
                lgs[k] = LG_k;
            }
        }
        LBAR();

        // ---- phase 2 (r1 waves only): s4l over LG quarter; h update
        if (r == 1) {
            float4 lq0 = lgv[q * 4 + 0], lq1 = lgv[q * 4 + 1],
                   lq2 = lgv[q * 4 + 2], lq3 = lgv[q * 4 + 3];
            float sLa = 0.f, sLb = 0.f;
            DOT4(sLa, wB0, lq0); DOT4(sLb, wB1, lq1); DOT4(sLa, wB2, lq2); DOT4(sLb, wB3, lq3);
            float s4l = qsum(sLa + sLb);
            float LGk = lgs[k];
            float gf = sigm(sA + s4l + uAc);     // sA=s4, uAc=u4
            h_k = LGk + gf * h_k;
            if (q == 0) ((_Float16*)hpv)[k] = (_Float16)h_k;               // next step
            if (q == 1) Ub[(size_t)lt * (B_SZ * 384) + k] = (_Float16)h_k; // for k_post
        }
        LBAR();

        uAc = uAn; uBc = uBn;
    }
    if (r == 1 && q == 0) hcarry[b * 128 + k] = h_k;
}

// ---------------- post: ability + y for all (t,b) in chunk, parallel --------------
__global__ __launch_bounds__(256) void k_post(
    const _Float16* __restrict__ U16, const _Float16* __restrict__ diff16,
    const float* __restrict__ disc, const h2* __restrict__ Wa16p,
    const float* __restrict__ ba, float* __restrict__ pred, int t0)
{
    __shared__ h2 WaS[128 * 64];     // swizzled: [c][j ^ (c&31)]
    __shared__ uint hS[4][64];       // per-wave h row (packed pairs)

    const int tid = threadIdx.x;
    const int w = tid >> 6, lane = tid & 63;

    for (int idx = tid; idx < 128 * 64; idx += 256) {
        int c = idx >> 6, j = idx & 63;
        WaS[(c << 6) + (j ^ (c & 31))] = Wa16p[idx];
    }
    __syncthreads();

    const int c1 = lane, c2 = lane + 64;
    const float ba1 = ba[c1], ba2 = ba[c2];
    const int x1 = c1 & 31, x2 = c2 & 31;

    for (int it = 0; it < 8; ++it) {
        int r = blockIdx.x * 32 + w * 8 + it;
        int b = r & 255, t = t0 + (r >> 8);
        const uint* hsrc = (const uint*)(U16 + (size_t)r * 384);
        hS[w][lane] = hsrc[lane];
        float d1 = (float)diff16[(size_t)(r + 512) * 128 + c1];
        float d2 = (float)diff16[(size_t)(r + 512) * 128 + c2];
        float g = disc[b * S_LEN + t + 1];
        __syncthreads();

        float dot1 = 0.f, dot2 = 0.f;
        const h2* hv = (const h2*)hS[w];
#pragma unroll
        for (int j = 0; j < 64; ++j) {
            h2 hj = hv[j];
            dot1 = fdot2(hj, WaS[(c1 << 6) + (j ^ x1)], dot1);
            dot2 = fdot2(hj, WaS[(c2 << 6) + (j ^ x2)], dot2);
        }
        float t1 = (sigm(dot1 + ba1) - d1) * d1;
        float t2 = (sigm(dot2 + ba2) - d2) * d2;
        float v = t1 + t2;
        v += __shfl_xor(v, 32, 64);
        v += __shfl_xor(v, 16, 64);
        v += __shfl_xor(v, 8, 64);
        v += __shfl_xor(v, 4, 64);
        v += __shfl_xor(v, 2, 64);
        v += __shfl_xor(v, 1, 64);
        if (lane == 0) pred[(size_t)b * S_LEN + t + 1] = sigm(g * v);
        __syncthreads();
    }
}

extern "C" void kernel_launch(void* const* d_in, const int* in_sizes, int n_in,
                              void* d_out, int out_size, void* d_ws, size_t ws_size,
                              hipStream_t stream)
{
    const int*   qseq  = (const int*)d_in[0];
    const int*   itseq = (const int*)d_in[1];
    const int*   utseq = (const int*)d_in[2];
    const int*   cseq  = (const int*)d_in[3];
    const float* h0    = (const float*)d_in[4];
    const float* Eq    = (const float*)d_in[5];
    const float* Eut   = (const float*)d_in[6];
    const float* Eit   = (const float*)d_in[7];
    const float* W1    = (const float*)d_in[8];
    const float* b1    = (const float*)d_in[9];
    const float* W2    = (const float*)d_in[10];
    const float* b2    = (const float*)d_in[11];
    const float* W3    = (const float*)d_in[12];
    const float* b3    = (const float*)d_in[13];
    const float* W4    = (const float*)d_in[14];
    const float* b4    = (const float*)d_in[15];
    const float* Wa    = (const float*)d_in[16];
    const float* ba    = (const float*)d_in[17];
    const float* Wd    = (const float*)d_in[18];
    const float* bd    = (const float*)d_in[19];
    const float* Wdisc = (const float*)d_in[20];
    const float* bdisc = (const float*)d_in[21];
    float* pred = (float*)d_out;

    // --- fixed-region layout ---
    char* p = (char*)d_ws;
    float* bz      = (float*)p;           p += 384 * 4;
    float* w1csum  = (float*)p;           p += 128 * 4;
    float* discb   = (float*)p;           p += 131072 * 4;
    float* hcarry  = (float*)p;           p += 32768 * 4;
    _Float16* Eq16  = (_Float16*)p;       p += 10001 * 128 * 2;
    _Float16* Eut16 = (_Float16*)p;       p += 1025 * 128 * 2;
    _Float16* Eit16 = (_Float16*)p;       p += 1025 * 128 * 2;
    _Float16* Wld16 = (_Float16*)p;       p += 256 * 256 * 2;
    _Float16* Wz16  = (_Float16*)p;       p += 384 * 384 * 2;
    h2*       Wa16p = (h2*)p;             p += 128 * 64 * 4;
    h2*       Wsc   = (h2*)p;             p += 1024 * 32 * 4;   // 128 KB
    const size_t fixed_bytes = (size_t)(p - (char*)d_ws);

    int T_CH = 4;
    {
        const int cands[8] = {511, 256, 128, 64, 32, 16, 8, 4};
        for (int ci = 0; ci < 8; ++ci) {
            size_t T = (size_t)cands[ci];
            size_t need = fixed_bytes + (T + 2) * 131072 + T * 196608;
            if (need <= ws_size) { T_CH = cands[ci]; break; }
        }
    }
    _Float16* learn16 = (_Float16*)p;     p += (size_t)(T_CH + 2) * 65536 * 2;
    _Float16* diff16  = (_Float16*)p;     p += (size_t)(T_CH + 2) * 65536 * 2;
    _Float16* U16     = (_Float16*)p;

    k_pack16<<<2048, 256, 0, stream>>>(W1, Wd, W2, W3, W4, b2, b3, b4, h0, Wa,
                                       Eq, Eut, Eit, Eq16, Eut16, Eit16,
                                       Wld16, Wz16, Wa16p, Wsc, bz, w1csum, hcarry, pred);
    k_disc<<<2048, 256, 0, stream>>>(qseq, Eq, Wdisc, bdisc, discb);

    for (int t0 = 0; t0 < S_LEN - 1; t0 += T_CH) {
        int T_len = S_LEN - 1 - t0; if (T_len > T_CH) T_len = T_CH;
        int s_lo = (t0 == 0) ? 0 : (t0 - 1);
        int s_hi = t0 + T_len + 1;
        int out_row0 = (s_lo - (t0 - 1)) * 256;
        k_mm_ld<<<dim3((s_hi - s_lo) * 2, 2), 256, 0, stream>>>(
            qseq, utseq, cseq, Eq16, Eut16, Wld16, b1, bd, w1csum,
            learn16, diff16, s_lo, out_row0);
        k_mm_u<<<dim3(T_len * 2, 3), 256, 0, stream>>>(
            itseq, Eit16, learn16, Wz16, bz, U16, t0);
        k_scan<<<256, 1024, 0, stream>>>(U16, hcarry, Wsc, T_len);
        k_post<<<T_len * 8, 256, 0, stream>>>(U16, diff16, discb, Wa16p, ba, pred, t0);
    }
}

// Round 10
// 861.649 us; speedup vs baseline: 1.0951x; 1.0951x over previous
//
#include <hip/hip_runtime.h>
#include <math.h>

#define S_LEN 512
#define B_SZ  256

typedef _Float16 f16x8 __attribute__((ext_vector_type(8)));
typedef _Float16 h2    __attribute__((ext_vector_type(2)));
typedef float    f32x4 __attribute__((ext_vector_type(4)));

__device__ __forceinline__ float sigm(float x) { return 1.0f / (1.0f + __expf(-x)); }

__device__ __forceinline__ float fdot2(h2 a, h2 b, float c) {
#if __has_builtin(__builtin_amdgcn_fdot2)
    return __builtin_amdgcn_fdot2(a, b, c, false);
#else
    return c + (float)a.x * (float)b.x + (float)a.y * (float)b.y;
#endif
}

// bit-reinterpret one float lane as a packed h2
#define H2C(f) __builtin_bit_cast(h2, f)
// 4 fdot2 along one float4(=4 h2) weight/act pair
#define DOT4(acc, W, H) do { \
    acc = fdot2(H2C((H).x), H2C((W).x), acc); \
    acc = fdot2(H2C((H).y), H2C((W).y), acc); \
    acc = fdot2(H2C((H).z), H2C((W).z), acc); \
    acc = fdot2(H2C((H).w), H2C((W).w), acc); } while (0)

// quad_perm butterfly add: after both, all 4 lanes of the quad hold the quad sum.
__device__ __forceinline__ float qsum1(float x) {
    int yi = __builtin_amdgcn_update_dpp(0, __builtin_bit_cast(int, x), 0xB1, 0xF, 0xF, true);
    return x + __builtin_bit_cast(float, yi);
}
__device__ __forceinline__ float qsum2(float x) {
    int yi = __builtin_amdgcn_update_dpp(0, __builtin_bit_cast(int, x), 0x4E, 0xF, 0xF, true);
    return x + __builtin_bit_cast(float, yi);
}
__device__ __forceinline__ float qsum(float x) { return qsum2(qsum1(x)); }

// raw barrier: drain LDS only; global loads/stores stay in flight
#define LBAR() do { \
    asm volatile("s_waitcnt lgkmcnt(0)" ::: "memory"); \
    __builtin_amdgcn_s_barrier(); \
    asm volatile("" ::: "memory"); \
} while (0)

// LDS tile byte offset with G4 XOR swizzle: row-major [128 rows][128 B]
__device__ __forceinline__ int swz(int row, int byte_in_row) {
    return row * 128 + (byte_in_row ^ ((row & 7) << 4));
}

// ---------------- pack: fp16 tables + packed weights (per-thread scan pack) -------
__global__ void k_pack16(const float* __restrict__ W1, const float* __restrict__ Wd,
                         const float* __restrict__ W2, const float* __restrict__ W3,
                         const float* __restrict__ W4, const float* __restrict__ b2,
                         const float* __restrict__ b3, const float* __restrict__ b4,
                         const float* __restrict__ h0, const float* __restrict__ Wa,
                         const float* __restrict__ Eq, const float* __restrict__ Eut,
                         const float* __restrict__ Eit,
                         _Float16* __restrict__ Eq16, _Float16* __restrict__ Eut16,
                         _Float16* __restrict__ Eit16,
                         _Float16* __restrict__ Wld16, _Float16* __restrict__ Wz16,
                         h2* __restrict__ Wa16p, h2* __restrict__ Wsc,
                         float* __restrict__ bz, float* __restrict__ w1csum,
                         float* __restrict__ hcarry, float* __restrict__ pred)
{
    int idx0 = blockIdx.x * blockDim.x + threadIdx.x;
    int stride = gridDim.x * blockDim.x;
    for (int i = idx0; i < 10001 * 128; i += stride) Eq16[i] = (_Float16)Eq[i];
    for (int i = idx0; i < 1025 * 128; i += stride) Eut16[i] = (_Float16)Eut[i];
    for (int i = idx0; i < 1025 * 128; i += stride) Eit16[i] = (_Float16)Eit[i];
    for (int idx = idx0; idx < 256 * 256; idx += stride) {
        int c = idx >> 8, j = idx & 255;
        float v;
        if (c < 128) v = W1[c * 306 + j];
        else         v = (j < 128) ? Wd[(c - 128) * 128 + j] : 0.f;
        Wld16[idx] = (_Float16)v;
    }
    for (int idx = idx0; idx < 384 * 384; idx += stride) {
        int c = idx / 384, j = idx - c * 384;
        float v;
        if (c < 128)      v = W2[c * 512 + j];
        else if (c < 256) v = W3[(c - 128) * 512 + j];
        else              v = (j >= 128 && j < 256) ? W4[(c - 256) * 384 + 128 + j] : 0.f;
        Wz16[idx] = (_Float16)v;
    }
    for (int idx = idx0; idx < 128 * 64; idx += stride) {
        int c = idx >> 6, j = idx & 63;
        h2 v; v.x = (_Float16)Wa[c * 128 + 2 * j]; v.y = (_Float16)Wa[c * 128 + 2 * j + 1];
        Wa16p[idx] = v;
    }
    // per-thread scan weights: slot = tid = k*4 + q (512 slots), 64 h2 each.
    // e: [0,16) W2h, [16,32) W3h, [32,48) W4h, [48,64) W4l — quarter q of row k.
    for (int idx = idx0; idx < 512 * 64; idx += stride) {
        int slot = idx >> 6, e = idx & 63;
        int q = slot & 3, kk = slot >> 2;
        int grp = e >> 4;
        int j = q * 32 + (e & 15) * 2;
        const float* src;
        if (grp == 0)      src = W2 + kk * 512 + 384 + j;
        else if (grp == 1) src = W3 + kk * 512 + 384 + j;
        else if (grp == 2) src = W4 + kk * 384 + j;
        else               src = W4 + kk * 384 + 128 + j;
        h2 v; v.x = (_Float16)src[0]; v.y = (_Float16)src[1];
        Wsc[idx] = v;
    }
    for (int idx = idx0; idx < 384; idx += stride)
        bz[idx] = (idx < 128) ? b2[idx] : (idx < 256 ? b3[idx - 128] : b4[idx - 256]);
    for (int idx = idx0; idx < 128; idx += stride) {
        float s = 0.f;
        for (int j = 0; j < 50; ++j) s += W1[idx * 306 + 256 + j];
        w1csum[idx] = s;
    }
    for (int idx = idx0; idx < 256 * 128; idx += stride) hcarry[idx] = h0[idx];
    for (int idx = idx0; idx < 256; idx += stride) pred[(size_t)idx * S_LEN] = 0.f;
}

// ---------------- disc: sigmoid(q . Wdisc + bdisc) * 10 (f32, full sequence) ------
__global__ __launch_bounds__(256) void k_disc(const int* __restrict__ qseq,
                                              const float* __restrict__ Eq,
                                              const float* __restrict__ Wdisc,
                                              const float* __restrict__ bdisc,
                                              float* __restrict__ disc)
{
    __shared__ float wd[128];
    __shared__ float bds;
    if (threadIdx.x < 128) wd[threadIdx.x] = Wdisc[threadIdx.x];
    if (threadIdx.x == 0) bds = bdisc[0];
    __syncthreads();
    int r = blockIdx.x * 64 + (threadIdx.x >> 2);
    int q4 = threadIdx.x & 3;
    const float* qe = Eq + (size_t)qseq[r] * 128 + q4 * 32;
    float s = 0.f;
#pragma unroll
    for (int j = 0; j < 32; ++j) s = fmaf(qe[j], wd[q4 * 32 + j], s);
    s += __shfl_xor(s, 1, 64);
    s += __shfl_xor(s, 2, 64);
    if (q4 == 0) disc[r] = sigm(s + bds) * 10.0f;
}

// ---------------- MFMA GEMM 1: learn (cb=0) / diff (cb=1); K=256 ------------------
__global__ __launch_bounds__(256) void k_mm_ld(
    const int* __restrict__ qseq, const int* __restrict__ utseq, const int* __restrict__ cseq,
    const _Float16* __restrict__ Eq16, const _Float16* __restrict__ Eut16,
    const _Float16* __restrict__ Wld16, const float* __restrict__ b1,
    const float* __restrict__ bd, const float* __restrict__ w1csum,
    _Float16* __restrict__ learn16, _Float16* __restrict__ diff16,
    int s_lo, int out_row0)
{
    __shared__ _Float16 As[128 * 64];
    __shared__ _Float16 Bs[128 * 64];
    __shared__ int   ridxq[128];
    __shared__ int   ridxut[128];
    __shared__ float rcorr[128];
    __shared__ float cS[128];
    __shared__ float c2S[128];

    const int tid = threadIdx.x;
    const int vr0 = blockIdx.x * 128;
    const int cb = blockIdx.y;

    if (tid < 128) {
        int vr = vr0 + tid;
        int b = vr & 255, s = s_lo + (vr >> 8);
        int rin = b * S_LEN + s;
        ridxq[tid] = qseq[rin];
        ridxut[tid] = utseq[rin];
        rcorr[tid] = (float)cseq[rin];
        cS[tid] = (cb == 0) ? w1csum[tid] : 0.f;
        c2S[tid] = (cb == 0) ? b1[tid] : bd[tid];
    }
    __syncthreads();

    const int wid = tid >> 6, lane = tid & 63;
    const int wr = wid >> 1, wc = wid & 1;
    const int lrow = lane & 15, lkg = lane >> 4;
    const int arow = tid >> 1, apart = tid & 1;

    f32x4 acc[4][4];
#pragma unroll
    for (int i = 0; i < 4; ++i)
#pragma unroll
        for (int j = 0; j < 4; ++j) acc[i][j] = (f32x4){0.f, 0.f, 0.f, 0.f};

    for (int kb = 0; kb < 4; ++kb) {
        int k0 = kb * 64;
        const _Float16* srcA = (k0 < 128)
            ? (Eq16 + (size_t)ridxq[arow] * 128 + k0 + apart * 32)
            : (Eut16 + (size_t)ridxut[arow] * 128 + (k0 - 128) + apart * 32);
        const _Float16* srcB = Wld16 + (size_t)(cb * 128 + arow) * 256 + k0 + apart * 32;
#pragma unroll
        for (int j = 0; j < 4; ++j) {
            float4 va = *(const float4*)(srcA + j * 8);
            float4 vb = *(const float4*)(srcB + j * 8);
            int boff = apart * 64 + j * 16;
            *(float4*)((char*)As + swz(arow, boff)) = va;
            *(float4*)((char*)Bs + swz(arow, boff)) = vb;
        }
        __syncthreads();
#pragma unroll
        for (int ks = 0; ks < 2; ++ks) {
            f16x8 af[4], bf[4];
#pragma unroll
            for (int f = 0; f < 4; ++f) {
                int ar = wr * 64 + f * 16 + lrow;
                af[f] = *(const f16x8*)((const char*)As + swz(ar, ks * 64 + lkg * 16));
                int br = wc * 64 + f * 16 + lrow;
                bf[f] = *(const f16x8*)((const char*)Bs + swz(br, ks * 64 + lkg * 16));
            }
#pragma unroll
            for (int fi = 0; fi < 4; ++fi)
#pragma unroll
                for (int fj = 0; fj < 4; ++fj)
                    acc[fi][fj] = __builtin_amdgcn_mfma_f32_16x16x32_f16(
                        af[fi], bf[fj], acc[fi][fj], 0, 0, 0);
        }
        __syncthreads();
    }

    if (cb == 0) {
#pragma unroll
        for (int fi = 0; fi < 4; ++fi) {
#pragma unroll
            for (int r = 0; r < 4; ++r) {
                int lr_ = wr * 64 + fi * 16 + (lane >> 4) * 4 + r;
                int grow = vr0 + out_row0 + lr_;
                float corr = rcorr[lr_];
#pragma unroll
                for (int fj = 0; fj < 4; ++fj) {
                    int col = wc * 64 + fj * 16 + (lane & 15);
                    float v = acc[fi][fj][r] + corr * cS[col] + c2S[col];
                    learn16[(size_t)grow * 128 + col] = (_Float16)v;
                }
            }
        }
    } else {
#pragma unroll
        for (int fi = 0; fi < 4; ++fi) {
#pragma unroll
            for (int r = 0; r < 4; ++r) {
                int lr_ = wr * 64 + fi * 16 + (lane >> 4) * 4 + r;
                int grow = vr0 + out_row0 + lr_;
#pragma unroll
                for (int fj = 0; fj < 4; ++fj) {
                    int col = wc * 64 + fj * 16 + (lane & 15);
                    float v = sigm(acc[fi][fj][r] + c2S[col]);
                    diff16[(size_t)grow * 128 + col] = (_Float16)v;
                }
            }
        }
    }
}

// ---------------- MFMA GEMM 2: U16[ur, cb*128..] , K=384 --------------------------
__global__ __launch_bounds__(256) void k_mm_u(
    const int* __restrict__ itseq, const _Float16* __restrict__ Eit16,
    const _Float16* __restrict__ learn16, const _Float16* __restrict__ Wz16,
    const float* __restrict__ bz, _Float16* __restrict__ U16, int t0)
{
    __shared__ _Float16 As[128 * 64];
    __shared__ _Float16 Bs[128 * 64];
    __shared__ int   itidx[128];
    __shared__ float bzS[128];

    const int tid = threadIdx.x;
    const int ur0 = blockIdx.x * 128;
    const int cb = blockIdx.y;
    const int t = t0 + (ur0 >> 8);
    const bool tzero = (t == 0);

    if (tid < 128) {
        int b = (ur0 + tid) & 255;
        itidx[tid] = itseq[b * S_LEN + t];
        bzS[tid] = bz[cb * 128 + tid];
    }
    __syncthreads();

    const int wid = tid >> 6, lane = tid & 63;
    const int wr = wid >> 1, wc = wid & 1;
    const int lrow = lane & 15, lkg = lane >> 4;
    const int arow = tid >> 1, apart = tid & 1;

    f32x4 acc[4][4];
#pragma unroll
    for (int i = 0; i < 4; ++i)
#pragma unroll
        for (int j = 0; j < 4; ++j) acc[i][j] = (f32x4){0.f, 0.f, 0.f, 0.f};

    for (int kb = 0; kb < 6; ++kb) {
        int k0 = kb * 64;
        int sec = k0 >> 7;
        int off = (k0 & 127) + apart * 32;
        const _Float16* srcA;
        if (sec == 0)      srcA = tzero ? nullptr : (learn16 + (size_t)(ur0 + arow) * 128 + off);
        else if (sec == 1) srcA = Eit16 + (size_t)itidx[arow] * 128 + off;
        else               srcA = learn16 + (size_t)(ur0 + arow + 256) * 128 + off;
        const _Float16* srcB = Wz16 + (size_t)(cb * 128 + arow) * 384 + k0 + apart * 32;
#pragma unroll
        for (int j = 0; j < 4; ++j) {
            float4 va;
            if (srcA) va = *(const float4*)(srcA + j * 8);
            else { va.x = va.y = va.z = va.w = 0.f; }
            float4 vb = *(const float4*)(srcB + j * 8);
            int boff = apart * 64 + j * 16;
            *(float4*)((char*)As + swz(arow, boff)) = va;
            *(float4*)((char*)Bs + swz(arow, boff)) = vb;
        }
        __syncthreads();
#pragma unroll
        for (int ks = 0; ks < 2; ++ks) {
            f16x8 af[4], bf[4];
#pragma unroll
            for (int f = 0; f < 4; ++f) {
                int ar = wr * 64 + f * 16 + lrow;
                af[f] = *(const f16x8*)((const char*)As + swz(ar, ks * 64 + lkg * 16));
                int br = wc * 64 + f * 16 + lrow;
                bf[f] = *(const f16x8*)((const char*)Bs + swz(br, ks * 64 + lkg * 16));
            }
#pragma unroll
            for (int fi = 0; fi < 4; ++fi)
#pragma unroll
                for (int fj = 0; fj < 4; ++fj)
                    acc[fi][fj] = __builtin_amdgcn_mfma_f32_16x16x32_f16(
                        af[fi], bf[fj], acc[fi][fj], 0, 0, 0);
        }
        __syncthreads();
    }

#pragma unroll
    for (int fi = 0; fi < 4; ++fi) {
#pragma unroll
        for (int r = 0; r < 4; ++r) {
            int lr_ = wr * 64 + fi * 16 + (lane >> 4) * 4 + r;
            int grow = ur0 + lr_;
#pragma unroll
            for (int fj = 0; fj < 4; ++fj) {
                int col = wc * 64 + fj * 16 + (lane & 15);
                float v = acc[fi][fj][r] + bzS[col];
                U16[(size_t)grow * 384 + cb * 128 + col] = (_Float16)v;
            }
        }
    }
}

// ---------------- scan v9: R8 structure, per-step global h-store -> LDS ring ------
__global__ __launch_bounds__(512) __attribute__((amdgpu_waves_per_eu(2, 2)))
void k_scan(_Float16* __restrict__ U16, float* __restrict__ hcarry,
            const h2* __restrict__ Wsc, int T_len)
{
    const int b = blockIdx.x;
    const int tid = threadIdx.x;
    const int k = tid >> 2;          // output channel 0..127
    const int q = tid & 3;           // j-quarter (32 elems = 16 h2)

    // 64 h2 of weights in 16 NAMED float4 locals (no arrays -> no scratch)
    const float4* wsrc = (const float4*)(Wsc + (size_t)tid * 64);
    float4 wA0 = wsrc[0],  wA1 = wsrc[1],  wA2 = wsrc[2],  wA3 = wsrc[3];   // W2h
    float4 wB0 = wsrc[4],  wB1 = wsrc[5],  wB2 = wsrc[6],  wB3 = wsrc[7];   // W3h
    float4 wC0 = wsrc[8],  wC1 = wsrc[9],  wC2 = wsrc[10], wC3 = wsrc[11];  // W4h
    float4 wD0 = wsrc[12], wD1 = wsrc[13], wD2 = wsrc[14], wD3 = wsrc[15];  // W4l

    __shared__ float4 hpv[16];   // 128 halfs of h
    __shared__ float4 lgv[16];   // 128 halfs of LG
    __shared__ __align__(16) _Float16 hist[64][128];   // 16 KB h-history ring

    float h_k = hcarry[b * 128 + k];   // f32 carried state on all lanes
    if (tid < 64) {
        h2 v;
        v.x = (_Float16)hcarry[b * 128 + 2 * tid];
        v.y = (_Float16)hcarry[b * 128 + 2 * tid + 1];
        ((h2*)hpv)[tid] = v;
    }
    __syncthreads();

    _Float16* Ub = U16 + (size_t)b * 384;
    float u2c = (float)Ub[k], u3c = (float)Ub[128 + k], u4c = (float)Ub[256 + k];

    for (int lt = 0; lt < T_len; ++lt) {
        float u2n = 0.f, u3n = 0.f, u4n = 0.f;
        if (lt + 1 < T_len) {
            const _Float16* Un = Ub + (size_t)(lt + 1) * (B_SZ * 384);
            u2n = (float)Un[k]; u3n = (float)Un[128 + k]; u4n = (float)Un[256 + k];
        }

        // ---- stage 1: s2,s3,s4 over h quarter (named regs only)
        float4 hq0 = hpv[q * 4 + 0], hq1 = hpv[q * 4 + 1],
               hq2 = hpv[q * 4 + 2], hq3 = hpv[q * 4 + 3];
        float s2a = 0.f, s2b = 0.f, s3a = 0.f, s3b = 0.f, s4a = 0.f, s4b = 0.f;
        DOT4(s2a, wA0, hq0); DOT4(s2b, wA1, hq1); DOT4(s2a, wA2, hq2); DOT4(s2b, wA3, hq3);
        DOT4(s3a, wB0, hq0); DOT4(s3b, wB1, hq1); DOT4(s3a, wB2, hq2); DOT4(s3b, wB3, hq3);
        DOT4(s4a, wC0, hq0); DOT4(s4b, wC1, hq1); DOT4(s4a, wC2, hq2); DOT4(s4b, wC3, hq3);
        float s2 = qsum(s2a + s2b);
        float s3 = qsum(s3a + s3b);
        float s4 = qsum(s4a + s4b);
        float LG_k = sigm(s3 + u3c) * sigm(2.f * (s2 + u2c));
        if (q == 0) ((_Float16*)lgv)[k] = (_Float16)LG_k;
        LBAR();

        // ---- stage 2: s4l over LG quarter; h update on all lanes
        float4 lq0 = lgv[q * 4 + 0], lq1 = lgv[q * 4 + 1],
               lq2 = lgv[q * 4 + 2], lq3 = lgv[q * 4 + 3];
        float sLa = 0.f, sLb = 0.f;
        DOT4(sLa, wD0, lq0); DOT4(sLb, wD1, lq1); DOT4(sLa, wD2, lq2); DOT4(sLb, wD3, lq3);
        float s4l = qsum(sLa + sLb);
        float gf = sigm(s4 + s4l + u4c);
        h_k = LG_k + gf * h_k;
        if (q == 0) ((_Float16*)hpv)[k] = (_Float16)h_k;      // next-step exchange
        if (q == 1) hist[lt & 63][k] = (_Float16)h_k;         // history ring (LDS)
        LBAR();

        // ---- batched flush of h history to global (replaces per-step store)
        if (((lt & 63) == 63) || (lt + 1 == T_len)) {
            int g0 = lt & ~63;
            int gn = lt - g0 + 1;                 // 1..64 steps in this group
            int s = tid >> 3;
            if (s < gn) {
                int c0 = (tid & 7) * 16;
                const float4* src = (const float4*)&hist[s][c0];
                float4 v0 = src[0], v1 = src[1];
                float4* dst = (float4*)(U16 + ((size_t)(g0 + s) * B_SZ + b) * 384 + c0);
                dst[0] = v0; dst[1] = v1;
            }
        }

        u2c = u2n; u3c = u3n; u4c = u4n;
    }
    if (q == 0) hcarry[b * 128 + k] = h_k;
}

// ---------------- post: ability + y for all (t,b) in chunk, parallel --------------
__global__ __launch_bounds__(256) void k_post(
    const _Float16* __restrict__ U16, const _Float16* __restrict__ diff16,
    const float* __restrict__ disc, const h2* __restrict__ Wa16p,
    const float* __restrict__ ba, float* __restrict__ pred, int t0)
{
    __shared__ h2 WaS[128 * 64];     // swizzled: [c][j ^ (c&31)]
    __shared__ uint hS[4][64];       // per-wave h row (packed pairs)

    const int tid = threadIdx.x;
    const int w = tid >> 6, lane = tid & 63;

    for (int idx = tid; idx < 128 * 64; idx += 256) {
        int c = idx >> 6, j = idx & 63;
        WaS[(c << 6) + (j ^ (c & 31))] = Wa16p[idx];
    }
    __syncthreads();

    const int c1 = lane, c2 = lane + 64;
    const float ba1 = ba[c1], ba2 = ba[c2];
    const int x1 = c1 & 31, x2 = c2 & 31;

    for (int it = 0; it < 8; ++it) {
        int r = blockIdx.x * 32 + w * 8 + it;
        int b = r & 255, t = t0 + (r >> 8);
        const uint* hsrc = (const uint*)(U16 + (size_t)r * 384);
        hS[w][lane] = hsrc[lane];
        float d1 = (float)diff16[(size_t)(r + 512) * 128 + c1];
        float d2 = (float)diff16[(size_t)(r + 512) * 128 + c2];
        float g = disc[b * S_LEN + t + 1];
        __syncthreads();

        float dot1 = 0.f, dot2 = 0.f;
        const h2* hv = (const h2*)hS[w];
#pragma unroll
        for (int j = 0; j < 64; ++j) {
            h2 hj = hv[j];
            dot1 = fdot2(hj, WaS[(c1 << 6) + (j ^ x1)], dot1);
            dot2 = fdot2(hj, WaS[(c2 << 6) + (j ^ x2)], dot2);
        }
        float t1 = (sigm(dot1 + ba1) - d1) * d1;
        float t2 = (sigm(dot2 + ba2) - d2) * d2;
        float v = t1 + t2;
        v += __shfl_xor(v, 32, 64);
        v += __shfl_xor(v, 16, 64);
        v += __shfl_xor(v, 8, 64);
        v += __shfl_xor(v, 4, 64);
        v += __shfl_xor(v, 2, 64);
        v += __shfl_xor(v, 1, 64);
        if (lane == 0) pred[(size_t)b * S_LEN + t + 1] = sigm(g * v);
        __syncthreads();
    }
}

extern "C" void kernel_launch(void* const* d_in, const int* in_sizes, int n_in,
                              void* d_out, int out_size, void* d_ws, size_t ws_size,
                              hipStream_t stream)
{
    const int*   qseq  = (const int*)d_in[0];
    const int*   itseq = (const int*)d_in[1];
    const int*   utseq = (const int*)d_in[2];
    const int*   cseq  = (const int*)d_in[3];
    const float* h0    = (const float*)d_in[4];
    const float* Eq    = (const float*)d_in[5];
    const float* Eut   = (const float*)d_in[6];
    const float* Eit   = (const float*)d_in[7];
    const float* W1    = (const float*)d_in[8];
    const float* b1    = (const float*)d_in[9];
    const float* W2    = (const float*)d_in[10];
    const float* b2    = (const float*)d_in[11];
    const float* W3    = (const float*)d_in[12];
    const float* b3    = (const float*)d_in[13];
    const float* W4    = (const float*)d_in[14];
    const float* b4    = (const float*)d_in[15];
    const float* Wa    = (const float*)d_in[16];
    const float* ba    = (const float*)d_in[17];
    const float* Wd    = (const float*)d_in[18];
    const float* bd    = (const float*)d_in[19];
    const float* Wdisc = (const float*)d_in[20];
    const float* bdisc = (const float*)d_in[21];
    float* pred = (float*)d_out;

    // --- fixed-region layout ---
    char* p = (char*)d_ws;
    float* bz      = (float*)p;           p += 384 * 4;
    float* w1csum  = (float*)p;           p += 128 * 4;
    float* discb   = (float*)p;           p += 131072 * 4;
    float* hcarry  = (float*)p;           p += 32768 * 4;
    _Float16* Eq16  = (_Float16*)p;       p += 10001 * 128 * 2;
    _Float16* Eut16 = (_Float16*)p;       p += 1025 * 128 * 2;
    _Float16* Eit16 = (_Float16*)p;       p += 1025 * 128 * 2;
    _Float16* Wld16 = (_Float16*)p;       p += 256 * 256 * 2;
    _Float16* Wz16  = (_Float16*)p;       p += 384 * 384 * 2;
    h2*       Wa16p = (h2*)p;             p += 128 * 64 * 4;
    h2*       Wsc   = (h2*)p;             p += 512 * 64 * 4;   // 128 KB
    const size_t fixed_bytes = (size_t)(p - (char*)d_ws);

    int T_CH = 4;
    {
        const int cands[8] = {511, 256, 128, 64, 32, 16, 8, 4};
        for (int ci = 0; ci < 8; ++ci) {
            size_t T = (size_t)cands[ci];
            size_t need = fixed_bytes + (T + 2) * 131072 + T * 196608;
            if (need <= ws_size) { T_CH = cands[ci]; break; }
        }
    }
    _Float16* learn16 = (_Float16*)p;     p += (size_t)(T_CH + 2) * 65536 * 2;
    _Float16* diff16  = (_Float16*)p;     p += (size_t)(T_CH + 2) * 65536 * 2;
    _Float16* U16     = (_Float16*)p;

    k_pack16<<<2048, 256, 0, stream>>>(W1, Wd, W2, W3, W4, b2, b3, b4, h0, Wa,
                                       Eq, Eut, Eit, Eq16, Eut16, Eit16,
                                       Wld16, Wz16, Wa16p, Wsc, bz, w1csum, hcarry, pred);
    k_disc<<<2048, 256, 0, stream>>>(qseq, Eq, Wdisc, bdisc, discb);

    for (int t0 = 0; t0 < S_LEN - 1; t0 += T_CH) {
        int T_len = S_LEN - 1 - t0; if (T_len > T_CH) T_len = T_CH;
        int s_lo = (t0 == 0) ? 0 : (t0 - 1);
        int s_hi = t0 + T_len + 1;
        int out_row0 = (s_lo - (t0 - 1)) * 256;
        k_mm_ld<<<dim3((s_hi - s_lo) * 2, 2), 256, 0, stream>>>(
            qseq, utseq, cseq, Eq16, Eut16, Wld16, b1, bd, w1csum,
            learn16, diff16, s_lo, out_row0);
        k_mm_u<<<dim3(T_len * 2, 3), 256, 0, stream>>>(
            itseq, Eit16, learn16, Wz16, bz, U16, t0);
        k_scan<<<256, 512, 0, stream>>>(U16, hcarry, Wsc, T_len);
        k_post<<<T_len * 8, 256, 0, stream>>>(U16, diff16, discb, Wa16p, ba, pred, t0);
    }
}

// Round 11
// 703.925 us; speedup vs baseline: 1.3405x; 1.2241x over previous
//
#include <hip/hip_runtime.h>
#include <math.h>

#define S_LEN 512
#define B_SZ  256

typedef _Float16 f16x8 __attribute__((ext_vector_type(8)));
typedef _Float16 h2    __attribute__((ext_vector_type(2)));
typedef float    f32x4 __attribute__((ext_vector_type(4)));

__device__ __forceinline__ float sigm(float x) { return 1.0f / (1.0f + __expf(-x)); }

__device__ __forceinline__ float fdot2(h2 a, h2 b, float c) {
#if __has_builtin(__builtin_amdgcn_fdot2)
    return __builtin_amdgcn_fdot2(a, b, c, false);
#else
    return c + (float)a.x * (float)b.x + (float)a.y * (float)b.y;
#endif
}

// bit-reinterpret one float lane as a packed h2
#define H2C(f) __builtin_bit_cast(h2, f)
// 4 fdot2 along one float4(=4 h2) weight/act pair
#define DOT4(acc, W, H) do { \
    acc = fdot2(H2C((H).x), H2C((W).x), acc); \
    acc = fdot2(H2C((H).y), H2C((W).y), acc); \
    acc = fdot2(H2C((H).z), H2C((W).z), acc); \
    acc = fdot2(H2C((H).w), H2C((W).w), acc); } while (0)

// quad_perm butterfly add: after both, all 4 lanes of the quad hold the quad sum.
__device__ __forceinline__ float qsum1(float x) {
    int yi = __builtin_amdgcn_update_dpp(0, __builtin_bit_cast(int, x), 0xB1, 0xF, 0xF, true);
    return x + __builtin_bit_cast(float, yi);
}
__device__ __forceinline__ float qsum2(float x) {
    int yi = __builtin_amdgcn_update_dpp(0, __builtin_bit_cast(int, x), 0x4E, 0xF, 0xF, true);
    return x + __builtin_bit_cast(float, yi);
}
__device__ __forceinline__ float qsum(float x) { return qsum2(qsum1(x)); }

// raw barrier: drain LDS only; global loads/stores stay in flight
#define LBAR() do { \
    asm volatile("s_waitcnt lgkmcnt(0)" ::: "memory"); \
    __builtin_amdgcn_s_barrier(); \
    asm volatile("" ::: "memory"); \
} while (0)

// LDS tile byte offset with G4 XOR swizzle: row-major [128 rows][128 B]
__device__ __forceinline__ int swz(int row, int byte_in_row) {
    return row * 128 + (byte_in_row ^ ((row & 7) << 4));
}

// ---------------- pack: fp16 tables + packed weights (per-thread scan pack) -------
__global__ void k_pack16(const float* __restrict__ W1, const float* __restrict__ Wd,
                         const float* __restrict__ W2, const float* __restrict__ W3,
                         const float* __restrict__ W4, const float* __restrict__ b2,
                         const float* __restrict__ b3, const float* __restrict__ b4,
                         const float* __restrict__ h0, const float* __restrict__ Wa,
                         const float* __restrict__ Eq, const float* __restrict__ Eut,
                         const float* __restrict__ Eit,
                         _Float16* __restrict__ Eq16, _Float16* __restrict__ Eut16,
                         _Float16* __restrict__ Eit16,
                         _Float16* __restrict__ Wld16, _Float16* __restrict__ Wz16,
                         _Float16* __restrict__ Wa16, h2* __restrict__ Wsc,
                         float* __restrict__ bz, float* __restrict__ w1csum,
                         float* __restrict__ hcarry, float* __restrict__ pred)
{
    int idx0 = blockIdx.x * blockDim.x + threadIdx.x;
    int stride = gridDim.x * blockDim.x;
    for (int i = idx0; i < 10001 * 128; i += stride) Eq16[i] = (_Float16)Eq[i];
    for (int i = idx0; i < 1025 * 128; i += stride) Eut16[i] = (_Float16)Eut[i];
    for (int i = idx0; i < 1025 * 128; i += stride) Eit16[i] = (_Float16)Eit[i];
    for (int idx = idx0; idx < 256 * 256; idx += stride) {
        int c = idx >> 8, j = idx & 255;
        float v;
        if (c < 128) v = W1[c * 306 + j];
        else         v = (j < 128) ? Wd[(c - 128) * 128 + j] : 0.f;
        Wld16[idx] = (_Float16)v;
    }
    for (int idx = idx0; idx < 384 * 384; idx += stride) {
        int c = idx / 384, j = idx - c * 384;
        float v;
        if (c < 128)      v = W2[c * 512 + j];
        else if (c < 256) v = W3[(c - 128) * 512 + j];
        else              v = (j >= 128 && j < 256) ? W4[(c - 256) * 384 + 128 + j] : 0.f;
        Wz16[idx] = (_Float16)v;
    }
    for (int idx = idx0; idx < 128 * 128; idx += stride)
        Wa16[idx] = (_Float16)Wa[idx];
    // per-thread scan weights: slot = tid = k*4 + q (512 slots), 64 h2 each.
    // e: [0,16) W2h, [16,32) W3h, [32,48) W4h, [48,64) W4l — quarter q of row k.
    for (int idx = idx0; idx < 512 * 64; idx += stride) {
        int slot = idx >> 6, e = idx & 63;
        int q = slot & 3, kk = slot >> 2;
        int grp = e >> 4;
        int j = q * 32 + (e & 15) * 2;
        const float* src;
        if (grp == 0)      src = W2 + kk * 512 + 384 + j;
        else if (grp == 1) src = W3 + kk * 512 + 384 + j;
        else if (grp == 2) src = W4 + kk * 384 + j;
        else               src = W4 + kk * 384 + 128 + j;
        h2 v; v.x = (_Float16)src[0]; v.y = (_Float16)src[1];
        Wsc[idx] = v;
    }
    for (int idx = idx0; idx < 384; idx += stride)
        bz[idx] = (idx < 128) ? b2[idx] : (idx < 256 ? b3[idx - 128] : b4[idx - 256]);
    for (int idx = idx0; idx < 128; idx += stride) {
        float s = 0.f;
        for (int j = 0; j < 50; ++j) s += W1[idx * 306 + 256 + j];
        w1csum[idx] = s;
    }
    for (int idx = idx0; idx < 256 * 128; idx += stride) hcarry[idx] = h0[idx];
    for (int idx = idx0; idx < 256; idx += stride) pred[(size_t)idx * S_LEN] = 0.f;
}

// ---------------- disc: sigmoid(q . Wdisc + bdisc) * 10 (f32, full sequence) ------
__global__ __launch_bounds__(256) void k_disc(const int* __restrict__ qseq,
                                              const float* __restrict__ Eq,
                                              const float* __restrict__ Wdisc,
                                              const float* __restrict__ bdisc,
                                              float* __restrict__ disc)
{
    __shared__ float wd[128];
    __shared__ float bds;
    if (threadIdx.x < 128) wd[threadIdx.x] = Wdisc[threadIdx.x];
    if (threadIdx.x == 0) bds = bdisc[0];
    __syncthreads();
    int r = blockIdx.x * 64 + (threadIdx.x >> 2);
    int q4 = threadIdx.x & 3;
    const float* qe = Eq + (size_t)qseq[r] * 128 + q4 * 32;
    float s = 0.f;
#pragma unroll
    for (int j = 0; j < 32; ++j) s = fmaf(qe[j], wd[q4 * 32 + j], s);
    s += __shfl_xor(s, 1, 64);
    s += __shfl_xor(s, 2, 64);
    if (q4 == 0) disc[r] = sigm(s + bds) * 10.0f;
}

// ---------------- MFMA GEMM 1: learn (cb=0) / diff (cb=1); K=256 ------------------
__global__ __launch_bounds__(256) void k_mm_ld(
    const int* __restrict__ qseq, const int* __restrict__ utseq, const int* __restrict__ cseq,
    const _Float16* __restrict__ Eq16, const _Float16* __restrict__ Eut16,
    const _Float16* __restrict__ Wld16, const float* __restrict__ b1,
    const float* __restrict__ bd, const float* __restrict__ w1csum,
    _Float16* __restrict__ learn16, _Float16* __restrict__ diff16,
    int s_lo, int out_row0)
{
    __shared__ _Float16 As[128 * 64];
    __shared__ _Float16 Bs[128 * 64];
    __shared__ int   ridxq[128];
    __shared__ int   ridxut[128];
    __shared__ float rcorr[128];
    __shared__ float cS[128];
    __shared__ float c2S[128];

    const int tid = threadIdx.x;
    const int vr0 = blockIdx.x * 128;
    const int cb = blockIdx.y;

    if (tid < 128) {
        int vr = vr0 + tid;
        int b = vr & 255, s = s_lo + (vr >> 8);
        int rin = b * S_LEN + s;
        ridxq[tid] = qseq[rin];
        ridxut[tid] = utseq[rin];
        rcorr[tid] = (float)cseq[rin];
        cS[tid] = (cb == 0) ? w1csum[tid] : 0.f;
        c2S[tid] = (cb == 0) ? b1[tid] : bd[tid];
    }
    __syncthreads();

    const int wid = tid >> 6, lane = tid & 63;
    const int wr = wid >> 1, wc = wid & 1;
    const int lrow = lane & 15, lkg = lane >> 4;
    const int arow = tid >> 1, apart = tid & 1;

    f32x4 acc[4][4];
#pragma unroll
    for (int i = 0; i < 4; ++i)
#pragma unroll
        for (int j = 0; j < 4; ++j) acc[i][j] = (f32x4){0.f, 0.f, 0.f, 0.f};

    for (int kb = 0; kb < 4; ++kb) {
        int k0 = kb * 64;
        const _Float16* srcA = (k0 < 128)
            ? (Eq16 + (size_t)ridxq[arow] * 128 + k0 + apart * 32)
            : (Eut16 + (size_t)ridxut[arow] * 128 + (k0 - 128) + apart * 32);
        const _Float16* srcB = Wld16 + (size_t)(cb * 128 + arow) * 256 + k0 + apart * 32;
#pragma unroll
        for (int j = 0; j < 4; ++j) {
            float4 va = *(const float4*)(srcA + j * 8);
            float4 vb = *(const float4*)(srcB + j * 8);
            int boff = apart * 64 + j * 16;
            *(float4*)((char*)As + swz(arow, boff)) = va;
            *(float4*)((char*)Bs + swz(arow, boff)) = vb;
        }
        __syncthreads();
#pragma unroll
        for (int ks = 0; ks < 2; ++ks) {
            f16x8 af[4], bf[4];
#pragma unroll
            for (int f = 0; f < 4; ++f) {
                int ar = wr * 64 + f * 16 + lrow;
                af[f] = *(const f16x8*)((const char*)As + swz(ar, ks * 64 + lkg * 16));
                int br = wc * 64 + f * 16 + lrow;
                bf[f] = *(const f16x8*)((const char*)Bs + swz(br, ks * 64 + lkg * 16));
            }
#pragma unroll
            for (int fi = 0; fi < 4; ++fi)
#pragma unroll
                for (int fj = 0; fj < 4; ++fj)
                    acc[fi][fj] = __builtin_amdgcn_mfma_f32_16x16x32_f16(
                        af[fi], bf[fj], acc[fi][fj], 0, 0, 0);
        }
        __syncthreads();
    }

    if (cb == 0) {
#pragma unroll
        for (int fi = 0; fi < 4; ++fi) {
#pragma unroll
            for (int r = 0; r < 4; ++r) {
                int lr_ = wr * 64 + fi * 16 + (lane >> 4) * 4 + r;
                int grow = vr0 + out_row0 + lr_;
                float corr = rcorr[lr_];
#pragma unroll
                for (int fj = 0; fj < 4; ++fj) {
                    int col = wc * 64 + fj * 16 + (lane & 15);
                    float v = acc[fi][fj][r] + corr * cS[col] + c2S[col];
                    learn16[(size_t)grow * 128 + col] = (_Float16)v;
                }
            }
        }
    } else {
#pragma unroll
        for (int fi = 0; fi < 4; ++fi) {
#pragma unroll
            for (int r = 0; r < 4; ++r) {
                int lr_ = wr * 64 + fi * 16 + (lane >> 4) * 4 + r;
                int grow = vr0 + out_row0 + lr_;
#pragma unroll
                for (int fj = 0; fj < 4; ++fj) {
                    int col = wc * 64 + fj * 16 + (lane & 15);
                    float v = sigm(acc[fi][fj][r] + c2S[col]);
                    diff16[(size_t)grow * 128 + col] = (_Float16)v;
                }
            }
        }
    }
}

// ---------------- MFMA GEMM 2: U16[ur, cb*128..] , K=384 --------------------------
__global__ __launch_bounds__(256) void k_mm_u(
    const int* __restrict__ itseq, const _Float16* __restrict__ Eit16,
    const _Float16* __restrict__ learn16, const _Float16* __restrict__ Wz16,
    const float* __restrict__ bz, _Float16* __restrict__ U16, int t0)
{
    __shared__ _Float16 As[128 * 64];
    __shared__ _Float16 Bs[128 * 64];
    __shared__ int   itidx[128];
    __shared__ float bzS[128];

    const int tid = threadIdx.x;
    const int ur0 = blockIdx.x * 128;
    const int cb = blockIdx.y;
    const int t = t0 + (ur0 >> 8);
    const bool tzero = (t == 0);

    if (tid < 128) {
        int b = (ur0 + tid) & 255;
        itidx[tid] = itseq[b * S_LEN + t];
        bzS[tid] = bz[cb * 128 + tid];
    }
    __syncthreads();

    const int wid = tid >> 6, lane = tid & 63;
    const int wr = wid >> 1, wc = wid & 1;
    const int lrow = lane & 15, lkg = lane >> 4;
    const int arow = tid >> 1, apart = tid & 1;

    f32x4 acc[4][4];
#pragma unroll
    for (int i = 0; i < 4; ++i)
#pragma unroll
        for (int j = 0; j < 4; ++j) acc[i][j] = (f32x4){0.f, 0.f, 0.f, 0.f};

    for (int kb = 0; kb < 6; ++kb) {
        int k0 = kb * 64;
        int sec = k0 >> 7;
        int off = (k0 & 127) + apart * 32;
        const _Float16* srcA;
        if (sec == 0)      srcA = tzero ? nullptr : (learn16 + (size_t)(ur0 + arow) * 128 + off);
        else if (sec == 1) srcA = Eit16 + (size_t)itidx[arow] * 128 + off;
        else               srcA = learn16 + (size_t)(ur0 + arow + 256) * 128 + off;
        const _Float16* srcB = Wz16 + (size_t)(cb * 128 + arow) * 384 + k0 + apart * 32;
#pragma unroll
        for (int j = 0; j < 4; ++j) {
            float4 va;
            if (srcA) va = *(const float4*)(srcA + j * 8);
            else { va.x = va.y = va.z = va.w = 0.f; }
            float4 vb = *(const float4*)(srcB + j * 8);
            int boff = apart * 64 + j * 16;
            *(float4*)((char*)As + swz(arow, boff)) = va;
            *(float4*)((char*)Bs + swz(arow, boff)) = vb;
        }
        __syncthreads();
#pragma unroll
        for (int ks = 0; ks < 2; ++ks) {
            f16x8 af[4], bf[4];
#pragma unroll
            for (int f = 0; f < 4; ++f) {
                int ar = wr * 64 + f * 16 + lrow;
                af[f] = *(const f16x8*)((const char*)As + swz(ar, ks * 64 + lkg * 16));
                int br = wc * 64 + f * 16 + lrow;
                bf[f] = *(const f16x8*)((const char*)Bs + swz(br, ks * 64 + lkg * 16));
            }
#pragma unroll
            for (int fi = 0; fi < 4; ++fi)
#pragma unroll
                for (int fj = 0; fj < 4; ++fj)
                    acc[fi][fj] = __builtin_amdgcn_mfma_f32_16x16x32_f16(
                        af[fi], bf[fj], acc[fi][fj], 0, 0, 0);
        }
        __syncthreads();
    }

#pragma unroll
    for (int fi = 0; fi < 4; ++fi) {
#pragma unroll
        for (int r = 0; r < 4; ++r) {
            int lr_ = wr * 64 + fi * 16 + (lane >> 4) * 4 + r;
            int grow = ur0 + lr_;
#pragma unroll
            for (int fj = 0; fj < 4; ++fj) {
                int col = wc * 64 + fj * 16 + (lane & 15);
                float v = acc[fi][fj][r] + bzS[col];
                U16[(size_t)grow * 384 + cb * 128 + col] = (_Float16)v;
            }
        }
    }
}

// ---------------- scan (R8 exact): named-register weights, 2 waves/EU -------------
__global__ __launch_bounds__(512) __attribute__((amdgpu_waves_per_eu(2, 2)))
void k_scan(_Float16* __restrict__ U16, float* __restrict__ hcarry,
            const h2* __restrict__ Wsc, int T_len)
{
    const int b = blockIdx.x;
    const int tid = threadIdx.x;
    const int k = tid >> 2;          // output channel 0..127
    const int q = tid & 3;           // j-quarter (32 elems = 16 h2)

    // 64 h2 of weights in 16 NAMED float4 locals (no arrays -> no scratch)
    const float4* wsrc = (const float4*)(Wsc + (size_t)tid * 64);
    float4 wA0 = wsrc[0],  wA1 = wsrc[1],  wA2 = wsrc[2],  wA3 = wsrc[3];   // W2h
    float4 wB0 = wsrc[4],  wB1 = wsrc[5],  wB2 = wsrc[6],  wB3 = wsrc[7];   // W3h
    float4 wC0 = wsrc[8],  wC1 = wsrc[9],  wC2 = wsrc[10], wC3 = wsrc[11];  // W4h
    float4 wD0 = wsrc[12], wD1 = wsrc[13], wD2 = wsrc[14], wD3 = wsrc[15];  // W4l

    __shared__ float4 hpv[16];   // 128 halfs of h
    __shared__ float4 lgv[16];   // 128 halfs of LG

    float h_k = hcarry[b * 128 + k];   // f32 carried state on all lanes
    if (tid < 64) {
        h2 v;
        v.x = (_Float16)hcarry[b * 128 + 2 * tid];
        v.y = (_Float16)hcarry[b * 128 + 2 * tid + 1];
        ((h2*)hpv)[tid] = v;
    }
    __syncthreads();

    _Float16* Ub = U16 + (size_t)b * 384;
    float u2c = (float)Ub[k], u3c = (float)Ub[128 + k], u4c = (float)Ub[256 + k];

    for (int lt = 0; lt < T_len; ++lt) {
        float u2n = 0.f, u3n = 0.f, u4n = 0.f;
        if (lt + 1 < T_len) {
            const _Float16* Un = Ub + (size_t)(lt + 1) * (B_SZ * 384);
            u2n = (float)Un[k]; u3n = (float)Un[128 + k]; u4n = (float)Un[256 + k];
        }

        // ---- stage 1: s2,s3,s4 over h quarter (named regs only)
        float4 hq0 = hpv[q * 4 + 0], hq1 = hpv[q * 4 + 1],
               hq2 = hpv[q * 4 + 2], hq3 = hpv[q * 4 + 3];
        float s2a = 0.f, s2b = 0.f, s3a = 0.f, s3b = 0.f, s4a = 0.f, s4b = 0.f;
        DOT4(s2a, wA0, hq0); DOT4(s2b, wA1, hq1); DOT4(s2a, wA2, hq2); DOT4(s2b, wA3, hq3);
        DOT4(s3a, wB0, hq0); DOT4(s3b, wB1, hq1); DOT4(s3a, wB2, hq2); DOT4(s3b, wB3, hq3);
        DOT4(s4a, wC0, hq0); DOT4(s4b, wC1, hq1); DOT4(s4a, wC2, hq2); DOT4(s4b, wC3, hq3);
        float s2 = qsum(s2a + s2b);
        float s3 = qsum(s3a + s3b);
        float s4 = qsum(s4a + s4b);
        float LG_k = sigm(s3 + u3c) * sigm(2.f * (s2 + u2c));
        if (q == 0) ((_Float16*)lgv)[k] = (_Float16)LG_k;
        LBAR();

        // ---- stage 2: s4l over LG quarter; h update on all lanes
        float4 lq0 = lgv[q * 4 + 0], lq1 = lgv[q * 4 + 1],
               lq2 = lgv[q * 4 + 2], lq3 = lgv[q * 4 + 3];
        float sLa = 0.f, sLb = 0.f;
        DOT4(sLa, wD0, lq0); DOT4(sLb, wD1, lq1); DOT4(sLa, wD2, lq2); DOT4(sLb, wD3, lq3);
        float s4l = qsum(sLa + sLb);
        float gf = sigm(s4 + s4l + u4c);
        h_k = LG_k + gf * h_k;
        if (q == 0) ((_Float16*)hpv)[k] = (_Float16)h_k;               // next step
        if (q == 1) Ub[(size_t)lt * (B_SZ * 384) + k] = (_Float16)h_k; // for k_mm_a
        LBAR();

        u2c = u2n; u3c = u3n; u4c = u4n;
    }
    if (q == 0) hcarry[b * 128 + k] = h_k;
}

// ---------------- MFMA GEMM 3 + fused readout: ability/term/y ---------------------
// rows r = lt*256 + b (chunk-local); h at U16[r*384 + 0..127]; d at diff16[(r+512)*128]
__global__ __launch_bounds__(256) void k_mm_a(
    const _Float16* __restrict__ U16, const _Float16* __restrict__ diff16,
    const float* __restrict__ disc, const _Float16* __restrict__ Wa16,
    const float* __restrict__ ba, float* __restrict__ pred, int t0)
{
    __shared__ _Float16 smem[2][128 * 64];   // A/B tiles; later d-tile [128][128]
    __shared__ float redbuf[128][2];
    __shared__ float baS[128];
    __shared__ float gS[128];

    const int tid = threadIdx.x;
    const int ur0 = blockIdx.x * 128;
    const int lt = ur0 >> 8;
    _Float16* As = smem[0];
    _Float16* Bs = smem[1];

    if (tid < 128) {
        baS[tid] = ba[tid];
        int r = ur0 + tid;
        int b = r & 255;
        gS[tid] = disc[b * S_LEN + t0 + lt + 1];
    }

    const int wid = tid >> 6, lane = tid & 63;
    const int wr = wid >> 1, wc = wid & 1;
    const int lrow = lane & 15, lkg = lane >> 4;
    const int arow = tid >> 1, apart = tid & 1;

    f32x4 acc[4][4];
#pragma unroll
    for (int i = 0; i < 4; ++i)
#pragma unroll
        for (int j = 0; j < 4; ++j) acc[i][j] = (f32x4){0.f, 0.f, 0.f, 0.f};

    for (int kb = 0; kb < 2; ++kb) {
        int k0 = kb * 64;
        const _Float16* srcA = U16 + (size_t)(ur0 + arow) * 384 + k0 + apart * 32;
        const _Float16* srcB = Wa16 + (size_t)arow * 128 + k0 + apart * 32;
#pragma unroll
        for (int j = 0; j < 4; ++j) {
            float4 va = *(const float4*)(srcA + j * 8);
            float4 vb = *(const float4*)(srcB + j * 8);
            int boff = apart * 64 + j * 16;
            *(float4*)((char*)As + swz(arow, boff)) = va;
            *(float4*)((char*)Bs + swz(arow, boff)) = vb;
        }
        __syncthreads();
#pragma unroll
        for (int ks = 0; ks < 2; ++ks) {
            f16x8 af[4], bf[4];
#pragma unroll
            for (int f = 0; f < 4; ++f) {
                int ar = wr * 64 + f * 16 + lrow;
                af[f] = *(const f16x8*)((const char*)As + swz(ar, ks * 64 + lkg * 16));
                int br = wc * 64 + f * 16 + lrow;
                bf[f] = *(const f16x8*)((const char*)Bs + swz(br, ks * 64 + lkg * 16));
            }
#pragma unroll
            for (int fi = 0; fi < 4; ++fi)
#pragma unroll
                for (int fj = 0; fj < 4; ++fj)
                    acc[fi][fj] = __builtin_amdgcn_mfma_f32_16x16x32_f16(
                        af[fi], bf[fj], acc[fi][fj], 0, 0, 0);
        }
        __syncthreads();
    }

    // stage d tile [128 rows][128 cols] into smem (32 KB, coalesced)
    {
        const float4* dsrc = (const float4*)(diff16 + (size_t)(ur0 + 512) * 128);
        float4* ddst = (float4*)smem;
        for (int i = tid; i < 2048; i += 256) ddst[i] = dsrc[i];
    }
    __syncthreads();

    const _Float16* dtile = (const _Float16*)smem;
#pragma unroll
    for (int fi = 0; fi < 4; ++fi) {
#pragma unroll
        for (int rr = 0; rr < 4; ++rr) {
            int row = wr * 64 + fi * 16 + (lane >> 4) * 4 + rr;
            float part = 0.f;
#pragma unroll
            for (int fj = 0; fj < 4; ++fj) {
                int col = wc * 64 + fj * 16 + (lane & 15);
                float d = (float)dtile[row * 128 + col];
                float ab = sigm(acc[fi][fj][rr] + baS[col]);
                part += (ab - d) * d;
            }
            part += __shfl_xor(part, 1, 64);
            part += __shfl_xor(part, 2, 64);
            part += __shfl_xor(part, 4, 64);
            part += __shfl_xor(part, 8, 64);
            if ((lane & 15) == 0) redbuf[row][wc] = part;
        }
    }
    __syncthreads();
    if (tid < 128) {
        int r = ur0 + tid;
        int b = r & 255;
        float v = redbuf[tid][0] + redbuf[tid][1];
        pred[(size_t)b * S_LEN + t0 + lt + 1] = sigm(gS[tid] * v);
    }
}

extern "C" void kernel_launch(void* const* d_in, const int* in_sizes, int n_in,
                              void* d_out, int out_size, void* d_ws, size_t ws_size,
                              hipStream_t stream)
{
    const int*   qseq  = (const int*)d_in[0];
    const int*   itseq = (const int*)d_in[1];
    const int*   utseq = (const int*)d_in[2];
    const int*   cseq  = (const int*)d_in[3];
    const float* h0    = (const float*)d_in[4];
    const float* Eq    = (const float*)d_in[5];
    const float* Eut   = (const float*)d_in[6];
    const float* Eit   = (const float*)d_in[7];
    const float* W1    = (const float*)d_in[8];
    const float* b1    = (const float*)d_in[9];
    const float* W2    = (const float*)d_in[10];
    const float* b2    = (const float*)d_in[11];
    const float* W3    = (const float*)d_in[12];
    const float* b3    = (const float*)d_in[13];
    const float* W4    = (const float*)d_in[14];
    const float* b4    = (const float*)d_in[15];
    const float* Wa    = (const float*)d_in[16];
    const float* ba    = (const float*)d_in[17];
    const float* Wd    = (const float*)d_in[18];
    const float* bd    = (const float*)d_in[19];
    const float* Wdisc = (const float*)d_in[20];
    const float* bdisc = (const float*)d_in[21];
    float* pred = (float*)d_out;

    // --- fixed-region layout ---
    char* p = (char*)d_ws;
    float* bz      = (float*)p;           p += 384 * 4;
    float* w1csum  = (float*)p;           p += 128 * 4;
    float* discb   = (float*)p;           p += 131072 * 4;
    float* hcarry  = (float*)p;           p += 32768 * 4;
    _Float16* Eq16  = (_Float16*)p;       p += 10001 * 128 * 2;
    _Float16* Eut16 = (_Float16*)p;       p += 1025 * 128 * 2;
    _Float16* Eit16 = (_Float16*)p;       p += 1025 * 128 * 2;
    _Float16* Wld16 = (_Float16*)p;       p += 256 * 256 * 2;
    _Float16* Wz16  = (_Float16*)p;       p += 384 * 384 * 2;
    _Float16* Wa16  = (_Float16*)p;       p += 128 * 128 * 2;
    h2*       Wsc   = (h2*)p;             p += 512 * 64 * 4;   // 128 KB
    const size_t fixed_bytes = (size_t)(p - (char*)d_ws);

    int T_CH = 4;
    {
        const int cands[8] = {511, 256, 128, 64, 32, 16, 8, 4};
        for (int ci = 0; ci < 8; ++ci) {
            size_t T = (size_t)cands[ci];
            size_t need = fixed_bytes + (T + 2) * 131072 + T * 196608;
            if (need <= ws_size) { T_CH = cands[ci]; break; }
        }
    }
    _Float16* learn16 = (_Float16*)p;     p += (size_t)(T_CH + 2) * 65536 * 2;
    _Float16* diff16  = (_Float16*)p;     p += (size_t)(T_CH + 2) * 65536 * 2;
    _Float16* U16     = (_Float16*)p;

    k_pack16<<<2048, 256, 0, stream>>>(W1, Wd, W2, W3, W4, b2, b3, b4, h0, Wa,
                                       Eq, Eut, Eit, Eq16, Eut16, Eit16,
                                       Wld16, Wz16, Wa16, Wsc, bz, w1csum, hcarry, pred);
    k_disc<<<2048, 256, 0, stream>>>(qseq, Eq, Wdisc, bdisc, discb);

    for (int t0 = 0; t0 < S_LEN - 1; t0 += T_CH) {
        int T_len = S_LEN - 1 - t0; if (T_len > T_CH) T_len = T_CH;
        int s_lo = (t0 == 0) ? 0 : (t0 - 1);
        int s_hi = t0 + T_len + 1;
        int out_row0 = (s_lo - (t0 - 1)) * 256;
        k_mm_ld<<<dim3((s_hi - s_lo) * 2, 2), 256, 0, stream>>>(
            qseq, utseq, cseq, Eq16, Eut16, Wld16, b1, bd, w1csum,
            learn16, diff16, s_lo, out_row0);
        k_mm_u<<<dim3(T_len * 2, 3), 256, 0, stream>>>(
            itseq, Eit16, learn16, Wz16, bz, U16, t0);
        k_scan<<<256, 512, 0, stream>>>(U16, hcarry, Wsc, T_len);
        k_mm_a<<<T_len * 2, 256, 0, stream>>>(U16, diff16, discb, Wa16, ba, pred, t0);
    }
}

// Round 12
// 657.441 us; speedup vs baseline: 1.4353x; 1.0707x over previous
//
#include <hip/hip_runtime.h>
#include <math.h>

#define S_LEN 512
#define B_SZ  256

typedef _Float16 f16x8 __attribute__((ext_vector_type(8)));
typedef _Float16 h2    __attribute__((ext_vector_type(2)));
typedef float    f32x4 __attribute__((ext_vector_type(4)));

__device__ __forceinline__ float sigm(float x) { return 1.0f / (1.0f + __expf(-x)); }

__device__ __forceinline__ float fdot2(h2 a, h2 b, float c) {
#if __has_builtin(__builtin_amdgcn_fdot2)
    return __builtin_amdgcn_fdot2(a, b, c, false);
#else
    return c + (float)a.x * (float)b.x + (float)a.y * (float)b.y;
#endif
}

// bit-reinterpret one float lane as a packed h2
#define H2C(f) __builtin_bit_cast(h2, f)
// 4 fdot2 along one float4(=4 h2) weight/act pair
#define DOT4(acc, W, H) do { \
    acc = fdot2(H2C((H).x), H2C((W).x), acc); \
    acc = fdot2(H2C((H).y), H2C((W).y), acc); \
    acc = fdot2(H2C((H).z), H2C((W).z), acc); \
    acc = fdot2(H2C((H).w), H2C((W).w), acc); } while (0)

// quad_perm butterfly add, xor-1 only: both lanes of a pair hold the pair sum.
__device__ __forceinline__ float qsum1(float x) {
    int yi = __builtin_amdgcn_update_dpp(0, __builtin_bit_cast(int, x), 0xB1, 0xF, 0xF, true);
    return x + __builtin_bit_cast(float, yi);
}

// raw barrier: drain LDS only; global loads/stores stay in flight
#define LBAR() do { \
    asm volatile("s_waitcnt lgkmcnt(0)" ::: "memory"); \
    __builtin_amdgcn_s_barrier(); \
    asm volatile("" ::: "memory"); \
} while (0)

// LDS tile byte offset with G4 XOR swizzle: row-major [128 rows][128 B]
__device__ __forceinline__ int swz(int row, int byte_in_row) {
    return row * 128 + (byte_in_row ^ ((row & 7) << 4));
}

// ---------------- pack: fp16 tables + packed weights (per-thread scan pack) -------
__global__ void k_pack16(const float* __restrict__ W1, const float* __restrict__ Wd,
                         const float* __restrict__ W2, const float* __restrict__ W3,
                         const float* __restrict__ W4, const float* __restrict__ b2,
                         const float* __restrict__ b3, const float* __restrict__ b4,
                         const float* __restrict__ h0, const float* __restrict__ Wa,
                         const float* __restrict__ Eq, const float* __restrict__ Eut,
                         const float* __restrict__ Eit,
                         _Float16* __restrict__ Eq16, _Float16* __restrict__ Eut16,
                         _Float16* __restrict__ Eit16,
                         _Float16* __restrict__ Wld16, _Float16* __restrict__ Wz16,
                         _Float16* __restrict__ Wa16, h2* __restrict__ Wsc,
                         float* __restrict__ bz, float* __restrict__ w1csum,
                         float* __restrict__ hcarry, float* __restrict__ pred)
{
    int idx0 = blockIdx.x * blockDim.x + threadIdx.x;
    int stride = gridDim.x * blockDim.x;
    for (int i = idx0; i < 10001 * 128; i += stride) Eq16[i] = (_Float16)Eq[i];
    for (int i = idx0; i < 1025 * 128; i += stride) Eut16[i] = (_Float16)Eut[i];
    for (int i = idx0; i < 1025 * 128; i += stride) Eit16[i] = (_Float16)Eit[i];
    for (int idx = idx0; idx < 256 * 256; idx += stride) {
        int c = idx >> 8, j = idx & 255;
        float v;
        if (c < 128) v = W1[c * 306 + j];
        else         v = (j < 128) ? Wd[(c - 128) * 128 + j] : 0.f;
        Wld16[idx] = (_Float16)v;
    }
    for (int idx = idx0; idx < 384 * 384; idx += stride) {
        int c = idx / 384, j = idx - c * 384;
        float v;
        if (c < 128)      v = W2[c * 512 + j];
        else if (c < 256) v = W3[(c - 128) * 512 + j];
        else              v = (j >= 128 && j < 256) ? W4[(c - 256) * 384 + 128 + j] : 0.f;
        Wz16[idx] = (_Float16)v;
    }
    for (int idx = idx0; idx < 128 * 128; idx += stride)
        Wa16[idx] = (_Float16)Wa[idx];
    // per-thread scan weights: slot = tid = k*2 + q (256 slots), 128 h2 each.
    // e: [0,32) W2h, [32,64) W3h, [64,96) W4h, [96,128) W4l — half q of row k.
    for (int idx = idx0; idx < 256 * 128; idx += stride) {
        int slot = idx >> 7, e = idx & 127;
        int q = slot & 1, kk = slot >> 1;
        int grp = e >> 5;
        int j = q * 64 + (e & 31) * 2;
        const float* src;
        if (grp == 0)      src = W2 + kk * 512 + 384 + j;
        else if (grp == 1) src = W3 + kk * 512 + 384 + j;
        else if (grp == 2) src = W4 + kk * 384 + j;
        else               src = W4 + kk * 384 + 128 + j;
        h2 v; v.x = (_Float16)src[0]; v.y = (_Float16)src[1];
        Wsc[idx] = v;
    }
    for (int idx = idx0; idx < 384; idx += stride)
        bz[idx] = (idx < 128) ? b2[idx] : (idx < 256 ? b3[idx - 128] : b4[idx - 256]);
    for (int idx = idx0; idx < 128; idx += stride) {
        float s = 0.f;
        for (int j = 0; j < 50; ++j) s += W1[idx * 306 + 256 + j];
        w1csum[idx] = s;
    }
    for (int idx = idx0; idx < 256 * 128; idx += stride) hcarry[idx] = h0[idx];
    for (int idx = idx0; idx < 256; idx += stride) pred[(size_t)idx * S_LEN] = 0.f;
}

// ---------------- disc: sigmoid(q . Wdisc + bdisc) * 10 (f32, full sequence) ------
__global__ __launch_bounds__(256) void k_disc(const int* __restrict__ qseq,
                                              const float* __restrict__ Eq,
                                              const float* __restrict__ Wdisc,
                                              const float* __restrict__ bdisc,
                                              float* __restrict__ disc)
{
    __shared__ float wd[128];
    __shared__ float bds;
    if (threadIdx.x < 128) wd[threadIdx.x] = Wdisc[threadIdx.x];
    if (threadIdx.x == 0) bds = bdisc[0];
    __syncthreads();
    int r = blockIdx.x * 64 + (threadIdx.x >> 2);
    int q4 = threadIdx.x & 3;
    const float* qe = Eq + (size_t)qseq[r] * 128 + q4 * 32;
    float s = 0.f;
#pragma unroll
    for (int j = 0; j < 32; ++j) s = fmaf(qe[j], wd[q4 * 32 + j], s);
    s += __shfl_xor(s, 1, 64);
    s += __shfl_xor(s, 2, 64);
    if (q4 == 0) disc[r] = sigm(s + bds) * 10.0f;
}

// ---------------- MFMA GEMM 1: learn (cb=0) / diff (cb=1); K=256 ------------------
__global__ __launch_bounds__(256) void k_mm_ld(
    const int* __restrict__ qseq, const int* __restrict__ utseq, const int* __restrict__ cseq,
    const _Float16* __restrict__ Eq16, const _Float16* __restrict__ Eut16,
    const _Float16* __restrict__ Wld16, const float* __restrict__ b1,
    const float* __restrict__ bd, const float* __restrict__ w1csum,
    _Float16* __restrict__ learn16, _Float16* __restrict__ diff16,
    int s_lo, int out_row0)
{
    __shared__ _Float16 As[128 * 64];
    __shared__ _Float16 Bs[128 * 64];
    __shared__ int   ridxq[128];
    __shared__ int   ridxut[128];
    __shared__ float rcorr[128];
    __shared__ float cS[128];
    __shared__ float c2S[128];

    const int tid = threadIdx.x;
    const int vr0 = blockIdx.x * 128;
    const int cb = blockIdx.y;

    if (tid < 128) {
        int vr = vr0 + tid;
        int b = vr & 255, s = s_lo + (vr >> 8);
        int rin = b * S_LEN + s;
        ridxq[tid] = qseq[rin];
        ridxut[tid] = utseq[rin];
        rcorr[tid] = (float)cseq[rin];
        cS[tid] = (cb == 0) ? w1csum[tid] : 0.f;
        c2S[tid] = (cb == 0) ? b1[tid] : bd[tid];
    }
    __syncthreads();

    const int wid = tid >> 6, lane = tid & 63;
    const int wr = wid >> 1, wc = wid & 1;
    const int lrow = lane & 15, lkg = lane >> 4;
    const int arow = tid >> 1, apart = tid & 1;

    f32x4 acc[4][4];
#pragma unroll
    for (int i = 0; i < 4; ++i)
#pragma unroll
        for (int j = 0; j < 4; ++j) acc[i][j] = (f32x4){0.f, 0.f, 0.f, 0.f};

    for (int kb = 0; kb < 4; ++kb) {
        int k0 = kb * 64;
        const _Float16* srcA = (k0 < 128)
            ? (Eq16 + (size_t)ridxq[arow] * 128 + k0 + apart * 32)
            : (Eut16 + (size_t)ridxut[arow] * 128 + (k0 - 128) + apart * 32);
        const _Float16* srcB = Wld16 + (size_t)(cb * 128 + arow) * 256 + k0 + apart * 32;
#pragma unroll
        for (int j = 0; j < 4; ++j) {
            float4 va = *(const float4*)(srcA + j * 8);
            float4 vb = *(const float4*)(srcB + j * 8);
            int boff = apart * 64 + j * 16;
            *(float4*)((char*)As + swz(arow, boff)) = va;
            *(float4*)((char*)Bs + swz(arow, boff)) = vb;
        }
        __syncthreads();
#pragma unroll
        for (int ks = 0; ks < 2; ++ks) {
            f16x8 af[4], bf[4];
#pragma unroll
            for (int f = 0; f < 4; ++f) {
                int ar = wr * 64 + f * 16 + lrow;
                af[f] = *(const f16x8*)((const char*)As + swz(ar, ks * 64 + lkg * 16));
                int br = wc * 64 + f * 16 + lrow;
                bf[f] = *(const f16x8*)((const char*)Bs + swz(br, ks * 64 + lkg * 16));
            }
#pragma unroll
            for (int fi = 0; fi < 4; ++fi)
#pragma unroll
                for (int fj = 0; fj < 4; ++fj)
                    acc[fi][fj] = __builtin_amdgcn_mfma_f32_16x16x32_f16(
                        af[fi], bf[fj], acc[fi][fj], 0, 0, 0);
        }
        __syncthreads();
    }

    if (cb == 0) {
#pragma unroll
        for (int fi = 0; fi < 4; ++fi) {
#pragma unroll
            for (int r = 0; r < 4; ++r) {
                int lr_ = wr * 64 + fi * 16 + (lane >> 4) * 4 + r;
                int grow = vr0 + out_row0 + lr_;
                float corr = rcorr[lr_];
#pragma unroll
                for (int fj = 0; fj < 4; ++fj) {
                    int col = wc * 64 + fj * 16 + (lane & 15);
                    float v = acc[fi][fj][r] + corr * cS[col] + c2S[col];
                    learn16[(size_t)grow * 128 + col] = (_Float16)v;
                }
            }
        }
    } else {
#pragma unroll
        for (int fi = 0; fi < 4; ++fi) {
#pragma unroll
            for (int r = 0; r < 4; ++r) {
                int lr_ = wr * 64 + fi * 16 + (lane >> 4) * 4 + r;
                int grow = vr0 + out_row0 + lr_;
#pragma unroll
                for (int fj = 0; fj < 4; ++fj) {
                    int col = wc * 64 + fj * 16 + (lane & 15);
                    float v = sigm(acc[fi][fj][r] + c2S[col]);
                    diff16[(size_t)grow * 128 + col] = (_Float16)v;
                }
            }
        }
    }
}

// ---------------- MFMA GEMM 2: U16[ur, cb*128..] , K=384 --------------------------
__global__ __launch_bounds__(256) void k_mm_u(
    const int* __restrict__ itseq, const _Float16* __restrict__ Eit16,
    const _Float16* __restrict__ learn16, const _Float16* __restrict__ Wz16,
    const float* __restrict__ bz, _Float16* __restrict__ U16, int t0)
{
    __shared__ _Float16 As[128 * 64];
    __shared__ _Float16 Bs[128 * 64];
    __shared__ int   itidx[128];
    __shared__ float bzS[128];

    const int tid = threadIdx.x;
    const int ur0 = blockIdx.x * 128;
    const int cb = blockIdx.y;
    const int t = t0 + (ur0 >> 8);
    const bool tzero = (t == 0);

    if (tid < 128) {
        int b = (ur0 + tid) & 255;
        itidx[tid] = itseq[b * S_LEN + t];
        bzS[tid] = bz[cb * 128 + tid];
    }
    __syncthreads();

    const int wid = tid >> 6, lane = tid & 63;
    const int wr = wid >> 1, wc = wid & 1;
    const int lrow = lane & 15, lkg = lane >> 4;
    const int arow = tid >> 1, apart = tid & 1;

    f32x4 acc[4][4];
#pragma unroll
    for (int i = 0; i < 4; ++i)
#pragma unroll
        for (int j = 0; j < 4; ++j) acc[i][j] = (f32x4){0.f, 0.f, 0.f, 0.f};

    for (int kb = 0; kb < 6; ++kb) {
        int k0 = kb * 64;
        int sec = k0 >> 7;
        int off = (k0 & 127) + apart * 32;
        const _Float16* srcA;
        if (sec == 0)      srcA = tzero ? nullptr : (learn16 + (size_t)(ur0 + arow) * 128 + off);
        else if (sec == 1) srcA = Eit16 + (size_t)itidx[arow] * 128 + off;
        else               srcA = learn16 + (size_t)(ur0 + arow + 256) * 128 + off;
        const _Float16* srcB = Wz16 + (size_t)(cb * 128 + arow) * 384 + k0 + apart * 32;
#pragma unroll
        for (int j = 0; j < 4; ++j) {
            float4 va;
            if (srcA) va = *(const float4*)(srcA + j * 8);
            else { va.x = va.y = va.z = va.w = 0.f; }
            float4 vb = *(const float4*)(srcB + j * 8);
            int boff = apart * 64 + j * 16;
            *(float4*)((char*)As + swz(arow, boff)) = va;
            *(float4*)((char*)Bs + swz(arow, boff)) = vb;
        }
        __syncthreads();
#pragma unroll
        for (int ks = 0; ks < 2; ++ks) {
            f16x8 af[4], bf[4];
#pragma unroll
            for (int f = 0; f < 4; ++f) {
                int ar = wr * 64 + f * 16 + lrow;
                af[f] = *(const f16x8*)((const char*)As + swz(ar, ks * 64 + lkg * 16));
                int br = wc * 64 + f * 16 + lrow;
                bf[f] = *(const f16x8*)((const char*)Bs + swz(br, ks * 64 + lkg * 16));
            }
#pragma unroll
            for (int fi = 0; fi < 4; ++fi)
#pragma unroll
                for (int fj = 0; fj < 4; ++fj)
                    acc[fi][fj] = __builtin_amdgcn_mfma_f32_16x16x32_f16(
                        af[fi], bf[fj], acc[fi][fj], 0, 0, 0);
        }
        __syncthreads();
    }

#pragma unroll
    for (int fi = 0; fi < 4; ++fi) {
#pragma unroll
        for (int r = 0; r < 4; ++r) {
            int lr_ = wr * 64 + fi * 16 + (lane >> 4) * 4 + r;
            int grow = ur0 + lr_;
#pragma unroll
            for (int fj = 0; fj < 4; ++fj) {
                int col = wc * 64 + fj * 16 + (lane & 15);
                float v = acc[fi][fj][r] + bzS[col];
                U16[(size_t)grow * 384 + cb * 128 + col] = (_Float16)v;
            }
        }
    }
}

// ---------------- scan v10: 256 thr (4 waves), (k, j-half), 32 named f4 weights ---
__global__ __launch_bounds__(256) __attribute__((amdgpu_waves_per_eu(1, 1)))
void k_scan(_Float16* __restrict__ U16, float* __restrict__ hcarry,
            const h2* __restrict__ Wsc, int T_len)
{
    const int b = blockIdx.x;
    const int tid = threadIdx.x;
    const int k = tid >> 1;          // output channel 0..127
    const int q = tid & 1;           // j-half (64 elems = 32 h2)

    // 128 h2 of weights in 32 NAMED float4 locals (no arrays -> no scratch)
    const float4* wsrc = (const float4*)(Wsc + (size_t)tid * 128);
    float4 wA0 = wsrc[0],  wA1 = wsrc[1],  wA2 = wsrc[2],  wA3 = wsrc[3];
    float4 wA4 = wsrc[4],  wA5 = wsrc[5],  wA6 = wsrc[6],  wA7 = wsrc[7];   // W2h
    float4 wB0 = wsrc[8],  wB1 = wsrc[9],  wB2 = wsrc[10], wB3 = wsrc[11];
    float4 wB4 = wsrc[12], wB5 = wsrc[13], wB6 = wsrc[14], wB7 = wsrc[15];  // W3h
    float4 wC0 = wsrc[16], wC1 = wsrc[17], wC2 = wsrc[18], wC3 = wsrc[19];
    float4 wC4 = wsrc[20], wC5 = wsrc[21], wC6 = wsrc[22], wC7 = wsrc[23];  // W4h
    float4 wD0 = wsrc[24], wD1 = wsrc[25], wD2 = wsrc[26], wD3 = wsrc[27];
    float4 wD4 = wsrc[28], wD5 = wsrc[29], wD6 = wsrc[30], wD7 = wsrc[31];  // W4l

    __shared__ float4 hpv[16];   // 128 halfs of h
    __shared__ float4 lgv[16];   // 128 halfs of LG

    float h_k = hcarry[b * 128 + k];   // f32 carried state on both lanes of the pair
    if (tid < 64) {
        h2 v;
        v.x = (_Float16)hcarry[b * 128 + 2 * tid];
        v.y = (_Float16)hcarry[b * 128 + 2 * tid + 1];
        ((h2*)hpv)[tid] = v;
    }
    __syncthreads();

    _Float16* Ub = U16 + (size_t)b * 384;
    float u2c = (float)Ub[k], u3c = (float)Ub[128 + k], u4c = (float)Ub[256 + k];

    for (int lt = 0; lt < T_len; ++lt) {
        float u2n = 0.f, u3n = 0.f, u4n = 0.f;
        if (lt + 1 < T_len) {
            const _Float16* Un = Ub + (size_t)(lt + 1) * (B_SZ * 384);
            u2n = (float)Un[k]; u3n = (float)Un[128 + k]; u4n = (float)Un[256 + k];
        }

        // ---- stage 1: s2,s3,s4 over h half (named regs only)
        float4 hq0 = hpv[q * 8 + 0], hq1 = hpv[q * 8 + 1],
               hq2 = hpv[q * 8 + 2], hq3 = hpv[q * 8 + 3],
               hq4 = hpv[q * 8 + 4], hq5 = hpv[q * 8 + 5],
               hq6 = hpv[q * 8 + 6], hq7 = hpv[q * 8 + 7];
        float s2a = 0.f, s2b = 0.f, s3a = 0.f, s3b = 0.f, s4a = 0.f, s4b = 0.f;
        DOT4(s2a, wA0, hq0); DOT4(s2b, wA1, hq1); DOT4(s2a, wA2, hq2); DOT4(s2b, wA3, hq3);
        DOT4(s2a, wA4, hq4); DOT4(s2b, wA5, hq5); DOT4(s2a, wA6, hq6); DOT4(s2b, wA7, hq7);
        DOT4(s3a, wB0, hq0); DOT4(s3b, wB1, hq1); DOT4(s3a, wB2, hq2); DOT4(s3b, wB3, hq3);
        DOT4(s3a, wB4, hq4); DOT4(s3b, wB5, hq5); DOT4(s3a, wB6, hq6); DOT4(s3b, wB7, hq7);
        DOT4(s4a, wC0, hq0); DOT4(s4b, wC1, hq1); DOT4(s4a, wC2, hq2); DOT4(s4b, wC3, hq3);
        DOT4(s4a, wC4, hq4); DOT4(s4b, wC5, hq5); DOT4(s4a, wC6, hq6); DOT4(s4b, wC7, hq7);
        float s2 = qsum1(s2a + s2b);
        float s3 = qsum1(s3a + s3b);
        float s4 = qsum1(s4a + s4b);
        float LG_k = sigm(s3 + u3c) * sigm(2.f * (s2 + u2c));
        if (q == 0) ((_Float16*)lgv)[k] = (_Float16)LG_k;
        LBAR();

        // ---- stage 2: s4l over LG half; h update on both lanes
        float4 lq0 = hpv == nullptr ? (float4){0,0,0,0} : lgv[q * 8 + 0];
        float4 lq1 = lgv[q * 8 + 1], lq2 = lgv[q * 8 + 2], lq3 = lgv[q * 8 + 3];
        float4 lq4 = lgv[q * 8 + 4], lq5 = lgv[q * 8 + 5],
               lq6 = lgv[q * 8 + 6], lq7 = lgv[q * 8 + 7];
        float sLa = 0.f, sLb = 0.f;
        DOT4(sLa, wD0, lq0); DOT4(sLb, wD1, lq1); DOT4(sLa, wD2, lq2); DOT4(sLb, wD3, lq3);
        DOT4(sLa, wD4, lq4); DOT4(sLb, wD5, lq5); DOT4(sLa, wD6, lq6); DOT4(sLb, wD7, lq7);
        float s4l = qsum1(sLa + sLb);
        float gf = sigm(s4 + s4l + u4c);
        h_k = LG_k + gf * h_k;
        if (q == 0) ((_Float16*)hpv)[k] = (_Float16)h_k;               // next step
        if (q == 1) Ub[(size_t)lt * (B_SZ * 384) + k] = (_Float16)h_k; // for k_mm_a
        LBAR();

        u2c = u2n; u3c = u3n; u4c = u4n;
    }
    if (q == 0) hcarry[b * 128 + k] = h_k;
}

// ---------------- MFMA GEMM 3 + fused readout: ability/term/y ---------------------
__global__ __launch_bounds__(256) void k_mm_a(
    const _Float16* __restrict__ U16, const _Float16* __restrict__ diff16,
    const float* __restrict__ disc, const _Float16* __restrict__ Wa16,
    const float* __restrict__ ba, float* __restrict__ pred, int t0)
{
    __shared__ _Float16 smem[2][128 * 64];   // A/B tiles; later d-tile [128][128]
    __shared__ float redbuf[128][2];
    __shared__ float baS[128];
    __shared__ float gS[128];

    const int tid = threadIdx.x;
    const int ur0 = blockIdx.x * 128;
    const int lt = ur0 >> 8;
    _Float16* As = smem[0];
    _Float16* Bs = smem[1];

    if (tid < 128) {
        baS[tid] = ba[tid];
        int r = ur0 + tid;
        int b = r & 255;
        gS[tid] = disc[b * S_LEN + t0 + lt + 1];
    }

    const int wid = tid >> 6, lane = tid & 63;
    const int wr = wid >> 1, wc = wid & 1;
    const int lrow = lane & 15, lkg = lane >> 4;
    const int arow = tid >> 1, apart = tid & 1;

    f32x4 acc[4][4];
#pragma unroll
    for (int i = 0; i < 4; ++i)
#pragma unroll
        for (int j = 0; j < 4; ++j) acc[i][j] = (f32x4){0.f, 0.f, 0.f, 0.f};

    for (int kb = 0; kb < 2; ++kb) {
        int k0 = kb * 64;
        const _Float16* srcA = U16 + (size_t)(ur0 + arow) * 384 + k0 + apart * 32;
        const _Float16* srcB = Wa16 + (size_t)arow * 128 + k0 + apart * 32;
#pragma unroll
        for (int j = 0; j < 4; ++j) {
            float4 va = *(const float4*)(srcA + j * 8);
            float4 vb = *(const float4*)(srcB + j * 8);
            int boff = apart * 64 + j * 16;
            *(float4*)((char*)As + swz(arow, boff)) = va;
            *(float4*)((char*)Bs + swz(arow, boff)) = vb;
        }
        __syncthreads();
#pragma unroll
        for (int ks = 0; ks < 2; ++ks) {
            f16x8 af[4], bf[4];
#pragma unroll
            for (int f = 0; f < 4; ++f) {
                int ar = wr * 64 + f * 16 + lrow;
                af[f] = *(const f16x8*)((const char*)As + swz(ar, ks * 64 + lkg * 16));
                int br = wc * 64 + f * 16 + lrow;
                bf[f] = *(const f16x8*)((const char*)Bs + swz(br, ks * 64 + lkg * 16));
            }
#pragma unroll
            for (int fi = 0; fi < 4; ++fi)
#pragma unroll
                for (int fj = 0; fj < 4; ++fj)
                    acc[fi][fj] = __builtin_amdgcn_mfma_f32_16x16x32_f16(
                        af[fi], bf[fj], acc[fi][fj], 0, 0, 0);
        }
        __syncthreads();
    }

    // stage d tile [128 rows][128 cols] into smem (32 KB, coalesced)
    {
        const float4* dsrc = (const float4*)(diff16 + (size_t)(ur0 + 512) * 128);
        float4* ddst = (float4*)smem;
        for (int i = tid; i < 2048; i += 256) ddst[i] = dsrc[i];
    }
    __syncthreads();

    const _Float16* dtile = (const _Float16*)smem;
#pragma unroll
    for (int fi = 0; fi < 4; ++fi) {
#pragma unroll
        for (int rr = 0; rr < 4; ++rr) {
            int row = wr * 64 + fi * 16 + (lane >> 4) * 4 + rr;
            float part = 0.f;
#pragma unroll
            for (int fj = 0; fj < 4; ++fj) {
                int col = wc * 64 + fj * 16 + (lane & 15);
                float d = (float)dtile[row * 128 + col];
                float ab = sigm(acc[fi][fj][rr] + baS[col]);
                part += (ab - d) * d;
            }
            part += __shfl_xor(part, 1, 64);
            part += __shfl_xor(part, 2, 64);
            part += __shfl_xor(part, 4, 64);
            part += __shfl_xor(part, 8, 64);
            if ((lane & 15) == 0) redbuf[row][wc] = part;
        }
    }
    __syncthreads();
    if (tid < 128) {
        int r = ur0 + tid;
        int b = r & 255;
        float v = redbuf[tid][0] + redbuf[tid][1];
        pred[(size_t)b * S_LEN + t0 + lt + 1] = sigm(gS[tid] * v);
    }
}

extern "C" void kernel_launch(void* const* d_in, const int* in_sizes, int n_in,
                              void* d_out, int out_size, void* d_ws, size_t ws_size,
                              hipStream_t stream)
{
    const int*   qseq  = (const int*)d_in[0];
    const int*   itseq = (const int*)d_in[1];
    const int*   utseq = (const int*)d_in[2];
    const int*   cseq  = (const int*)d_in[3];
    const float* h0    = (const float*)d_in[4];
    const float* Eq    = (const float*)d_in[5];
    const float* Eut   = (const float*)d_in[6];
    const float* Eit   = (const float*)d_in[7];
    const float* W1    = (const float*)d_in[8];
    const float* b1    = (const float*)d_in[9];
    const float* W2    = (const float*)d_in[10];
    const float* b2    = (const float*)d_in[11];
    const float* W3    = (const float*)d_in[12];
    const float* b3    = (const float*)d_in[13];
    const float* W4    = (const float*)d_in[14];
    const float* b4    = (const float*)d_in[15];
    const float* Wa    = (const float*)d_in[16];
    const float* ba    = (const float*)d_in[17];
    const float* Wd    = (const float*)d_in[18];
    const float* bd    = (const float*)d_in[19];
    const float* Wdisc = (const float*)d_in[20];
    const float* bdisc = (const float*)d_in[21];
    float* pred = (float*)d_out;

    // --- fixed-region layout ---
    char* p = (char*)d_ws;
    float* bz      = (float*)p;           p += 384 * 4;
    float* w1csum  = (float*)p;           p += 128 * 4;
    float* discb   = (float*)p;           p += 131072 * 4;
    float* hcarry  = (float*)p;           p += 32768 * 4;
    _Float16* Eq16  = (_Float16*)p;       p += 10001 * 128 * 2;
    _Float16* Eut16 = (_Float16*)p;       p += 1025 * 128 * 2;
    _Float16* Eit16 = (_Float16*)p;       p += 1025 * 128 * 2;
    _Float16* Wld16 = (_Float16*)p;       p += 256 * 256 * 2;
    _Float16* Wz16  = (_Float16*)p;       p += 384 * 384 * 2;
    _Float16* Wa16  = (_Float16*)p;       p += 128 * 128 * 2;
    h2*       Wsc   = (h2*)p;             p += 256 * 128 * 4;   // 128 KB
    const size_t fixed_bytes = (size_t)(p - (char*)d_ws);

    int T_CH = 4;
    {
        const int cands[8] = {511, 256, 128, 64, 32, 16, 8, 4};
        for (int ci = 0; ci < 8; ++ci) {
            size_t T = (size_t)cands[ci];
            size_t need = fixed_bytes + (T + 2) * 131072 + T * 196608;
            if (need <= ws_size) { T_CH = cands[ci]; break; }
        }
    }
    _Float16* learn16 = (_Float16*)p;     p += (size_t)(T_CH + 2) * 65536 * 2;
    _Float16* diff16  = (_Float16*)p;     p += (size_t)(T_CH + 2) * 65536 * 2;
    _Float16* U16     = (_Float16*)p;

    k_pack16<<<2048, 256, 0, stream>>>(W1, Wd, W2, W3, W4, b2, b3, b4, h0, Wa,
                                       Eq, Eut, Eit, Eq16, Eut16, Eit16,
                                       Wld16, Wz16, Wa16, Wsc, bz, w1csum, hcarry, pred);
    k_disc<<<2048, 256, 0, stream>>>(qseq, Eq, Wdisc, bdisc, discb);

    for (int t0 = 0; t0 < S_LEN - 1; t0 += T_CH) {
        int T_len = S_LEN - 1 - t0; if (T_len > T_CH) T_len = T_CH;
        int s_lo = (t0 == 0) ? 0 : (t0 - 1);
        int s_hi = t0 + T_len + 1;
        int out_row0 = (s_lo - (t0 - 1)) * 256;
        k_mm_ld<<<dim3((s_hi - s_lo) * 2, 2), 256, 0, stream>>>(
            qseq, utseq, cseq, Eq16, Eut16, Wld16, b1, bd, w1csum,
            learn16, diff16, s_lo, out_row0);
        k_mm_u<<<dim3(T_len * 2, 3), 256, 0, stream>>>(
            itseq, Eit16, learn16, Wz16, bz, U16, t0);
        k_scan<<<256, 256, 0, stream>>>(U16, hcarry, Wsc, T_len);
        k_mm_a<<<T_len * 2, 256, 0, stream>>>(U16, diff16, discb, Wa16, ba, pred, t0);
    }
}